// Round 2
// baseline (2952.643 us; speedup 1.0000x reference)
//
#include <hip/hip_runtime.h>

typedef unsigned short u16;
typedef unsigned int u32;

#define WD 160
#define HW 25600
#define NPIXF 204800.0f
#define BNEPS 1e-5f

__device__ __forceinline__ float bf2f(u16 u) { return __uint_as_float(((u32)u) << 16); }
__device__ __forceinline__ u16 f2bf(float f) {
    u32 x = __float_as_uint(f);
    return (u16)((x + 0x7FFFu + ((x >> 16) & 1u)) >> 16);
}
__device__ __forceinline__ u32 pack2(float a, float b) {
    return (u32)f2bf(a) | ((u32)f2bf(b) << 16);
}

// ---------------------------------------------------------------------------
// conv1: 1x1 conv (64 -> 128) + bias. Input x f32. Output c1 as packed bf16
// into the byte-region of d_out channels [0,64) of each batch (u16 batch
// stride 256*HW). Also accumulates per-channel sum/sumsq (pre-rounding f32).
// Block: 64 pixels x 128 oc; 256 thr: tx(16)->4px, ty(16)->8oc.
// ---------------------------------------------------------------------------
__global__ __launch_bounds__(256) void k_conv1(
    const float* __restrict__ x, const float* __restrict__ w1,
    const float* __restrict__ bias, u16* __restrict__ c1, float* __restrict__ stats)
{
    __shared__ __align__(16) float Xs[64][68];
    __shared__ __align__(16) float Ws[64][136];
    const int tid = threadIdx.x;
    const int b = blockIdx.y;
    const int px0 = blockIdx.x * 64;

    for (int d = tid; d < 8192; d += 256)
        Ws[d & 63][d >> 6] = w1[d];             // w1[oc][ic] -> Ws[ic][oc], coalesced read
    for (int d = tid; d < 1024; d += 256) {
        int i = d >> 4, j4 = (d & 15) * 4;
        *(float4*)&Xs[i][j4] = *(const float4*)&x[(size_t)(b * 64 + i) * HW + px0 + j4];
    }
    __syncthreads();

    const int tx = tid & 15, ty = tid >> 4;
    float acc[8][4];
#pragma unroll
    for (int o = 0; o < 8; ++o)
#pragma unroll
        for (int j = 0; j < 4; ++j) acc[o][j] = 0.f;

#pragma unroll 4
    for (int i = 0; i < 64; ++i) {
        const float4 xv = *(const float4*)&Xs[i][tx * 4];
        const float4 w0 = *(const float4*)&Ws[i][ty * 8];
        const float4 wq = *(const float4*)&Ws[i][ty * 8 + 4];
        const float xr[4] = {xv.x, xv.y, xv.z, xv.w};
        const float wv[8] = {w0.x, w0.y, w0.z, w0.w, wq.x, wq.y, wq.z, wq.w};
#pragma unroll
        for (int o = 0; o < 8; ++o)
#pragma unroll
            for (int j = 0; j < 4; ++j)
                acc[o][j] = fmaf(wv[o], xr[j], acc[o][j]);
    }

    u16* outb = c1 + (size_t)b * 256 * HW;       // batch byte-span start as u16*
    const int pxb = px0 + tx * 4;
#pragma unroll
    for (int o = 0; o < 8; ++o) {
        const int oc = ty * 8 + o;
        const float bv = bias[oc];
        float v0 = acc[o][0] + bv, v1 = acc[o][1] + bv;
        float v2 = acc[o][2] + bv, v3 = acc[o][3] + bv;
        float s = v0 + v1 + v2 + v3;
        float s2 = v0 * v0 + v1 * v1 + v2 * v2 + v3 * v3;
        uint2 q = make_uint2(pack2(v0, v1), pack2(v2, v3));
        *(uint2*)(outb + (size_t)oc * HW + pxb) = q;
#pragma unroll
        for (int off = 1; off < 16; off <<= 1) {
            s  += __shfl_xor(s, off);
            s2 += __shfl_xor(s2, off);
        }
        if (tx == 0) {
            atomicAdd(&stats[oc * 2], s);
            atomicAdd(&stats[oc * 2 + 1], s2);
        }
    }
}

// ---------------------------------------------------------------------------
// generic 3x3 conv (CIN -> 64) + bias, raw f32 out + stats. Optional BN
// affine+relu applied to the input on load (AFF), optional bf16 input (BF16IN).
// Block: 32w x 8h pixels, 64 oc; 256 thr: tx(4)->8px, ry(8), ty(8)->8oc.
// bstride = input batch stride in elements (u16 elements when BF16IN).
// ---------------------------------------------------------------------------
template<int CIN, bool AFF, bool BF16IN>
__global__ __launch_bounds__(256) void k_conv3(
    const void* __restrict__ inv, long bstride,
    const float* __restrict__ w, const float* __restrict__ bias,
    const float* __restrict__ stats_in, const float* __restrict__ g_in,
    const float* __restrict__ be_in,
    float* __restrict__ out, int OUTC, int coff, float* __restrict__ stats_out)
{
    __shared__ __align__(16) float pat[8][10][36];
    __shared__ __align__(16) float wl[8][9][68];
    __shared__ float asc[CIN];
    __shared__ float abi[CIN];

    const int tid = threadIdx.x;
    const int b = blockIdx.z;
    const int x0 = blockIdx.x * 32, y0 = blockIdx.y * 8;

    if constexpr (AFF) {
        for (int c = tid; c < CIN; c += 256) {
            float m = stats_in[c * 2] / NPIXF;
            float v = stats_in[c * 2 + 1] / NPIXF - m * m;
            float sc = g_in[c] * rsqrtf(v + BNEPS);
            asc[c] = sc;
            abi[c] = be_in[c] - m * sc;
        }
    }

    const int tx = tid & 3, ry = (tid >> 2) & 7, ty = tid >> 5;
    float acc[8][8];
#pragma unroll
    for (int o = 0; o < 8; ++o)
#pragma unroll
        for (int j = 0; j < 8; ++j) acc[o][j] = 0.f;

    for (int icg = 0; icg < CIN / 8; ++icg) {
        __syncthreads();  // protects pat/wl reuse; on iter 0 also orders asc writes
        for (int d = tid; d < 2720; d += 256) {
            int ic = d / 340, rem = d - ic * 340;
            int r = rem / 34, cc = rem - r * 34;
            int gy = y0 + r - 1, gx = x0 + cc - 1;
            float v = 0.f;
            if ((unsigned)gy < 160u && (unsigned)gx < 160u) {
                int icn = icg * 8 + ic;
                if constexpr (BF16IN)
                    v = bf2f(((const u16*)inv)[(size_t)b * bstride + (size_t)icn * HW + gy * WD + gx]);
                else
                    v = ((const float*)inv)[(size_t)b * bstride + (size_t)icn * HW + gy * WD + gx];
                if constexpr (AFF) v = fmaxf(0.f, v * asc[icn] + abi[icn]);
            }
            pat[ic][r][cc] = v;
        }
        // weights: w[oc][ic][tap] -> wl[ic][tap][oc]; reads coalesced in 72-chunks
        for (int d = tid; d < 4608; d += 256) {
            int oc = d / 72, r = d - oc * 72;
            int ic = r / 9, tap = r - ic * 9;
            wl[ic][tap][oc] = w[(size_t)oc * CIN * 9 + (size_t)icg * 72 + r];
        }
        __syncthreads();

        for (int ic = 0; ic < 8; ++ic) {
#pragma unroll
            for (int dy = 0; dy < 3; ++dy) {
                const float* pr = &pat[ic][ry + dy][tx * 8];
                const float4 xa = *(const float4*)pr;
                const float4 xb = *(const float4*)(pr + 4);
                const float4 xc = *(const float4*)(pr + 8);
                const float xr[12] = {xa.x, xa.y, xa.z, xa.w,
                                      xb.x, xb.y, xb.z, xb.w,
                                      xc.x, xc.y, xc.z, xc.w};
#pragma unroll
                for (int dx = 0; dx < 3; ++dx) {
                    const float4 w0 = *(const float4*)&wl[ic][dy * 3 + dx][ty * 8];
                    const float4 wq = *(const float4*)&wl[ic][dy * 3 + dx][ty * 8 + 4];
                    const float wv[8] = {w0.x, w0.y, w0.z, w0.w, wq.x, wq.y, wq.z, wq.w};
#pragma unroll
                    for (int o = 0; o < 8; ++o)
#pragma unroll
                        for (int j = 0; j < 8; ++j)
                            acc[o][j] = fmaf(wv[o], xr[j + dx], acc[o][j]);
                }
            }
        }
    }

    const int gy = y0 + ry, gx0 = x0 + tx * 8;
    float* obase = out + (size_t)(b * OUTC + coff) * HW + gy * WD + gx0;
#pragma unroll
    for (int o = 0; o < 8; ++o) {
        const int oc = ty * 8 + o;
        const float bv = bias[oc];
        float v[8];
        float s = 0.f, s2 = 0.f;
#pragma unroll
        for (int j = 0; j < 8; ++j) {
            v[j] = acc[o][j] + bv;
            s += v[j];
            s2 += v[j] * v[j];
        }
        float4 qa = make_float4(v[0], v[1], v[2], v[3]);
        float4 qb = make_float4(v[4], v[5], v[6], v[7]);
        *(float4*)(obase + (size_t)oc * HW) = qa;
        *(float4*)(obase + (size_t)oc * HW + 4) = qb;
#pragma unroll
        for (int off = 1; off < 32; off <<= 1) {
            s  += __shfl_xor(s, off);
            s2 += __shfl_xor(s2, off);
        }
        if ((tid & 31) == 0) {
            atomicAdd(&stats_out[oc * 2], s);
            atomicAdd(&stats_out[oc * 2 + 1], s2);
        }
    }
}

// ---------------------------------------------------------------------------
// sobel: reads raw2 f32 from out ch[64,128) slots applying BN2 affine + relu,
// writes edge f32 into out ch[0,64) slots. 8 nonzero taps of the combined 5x5.
// ---------------------------------------------------------------------------
__global__ __launch_bounds__(256) void k_sobel(
    float* __restrict__ F, const float* __restrict__ st,
    const float* __restrict__ g, const float* __restrict__ be)
{
    const int tid = threadIdx.x;
    const int c = blockIdx.z & 63, b = blockIdx.z >> 6;
    const int x0 = blockIdx.x * 32, y0 = blockIdx.y * 8;
    const float m = st[c * 2] / NPIXF;
    const float var = st[c * 2 + 1] / NPIXF - m * m;
    const float sc = g[c] * rsqrtf(var + BNEPS);
    const float bi = be[c] - m * sc;
    const float* base = F + ((size_t)b * 128 + 64 + c) * HW;
    float* dst = F + ((size_t)b * 128 + c) * HW;
    const int px = tid & 31, ry = tid >> 5;
    const int gx = x0 + px, gy = y0 + ry;
    auto LD = [&](int yy, int xx) -> float {
        if ((unsigned)yy >= 160u || (unsigned)xx >= 160u) return 0.f;
        return fmaxf(0.f, base[yy * WD + xx] * sc + bi);
    };
    float r = 4.f * LD(gy - 1, gx - 1) + 4.f * LD(gy - 1, gx)
            - 2.f * LD(gy, gx - 2) - 8.f * LD(gy, gx - 1)
            + 8.f * LD(gy, gx + 1) + 2.f * LD(gy, gx + 2)
            - 4.f * LD(gy + 1, gx) - 4.f * LD(gy + 1, gx + 1);
    dst[gy * WD + gx] = r;
}

// ---------------------------------------------------------------------------
// final in-place BN+ReLU on d_out: ch<64 -> stage4 (skip), ch>=64 -> stage3.
// ---------------------------------------------------------------------------
__global__ __launch_bounds__(256) void k_bnrelu(
    float* __restrict__ io, const float* __restrict__ s3, const float* __restrict__ s4,
    const float* __restrict__ g3, const float* __restrict__ be3,
    const float* __restrict__ g4, const float* __restrict__ be4)
{
    const size_t e = (size_t)(blockIdx.x * 256 + threadIdx.x) * 8;
    const int cg = (int)((e / HW) & 127);
    float sc, bi;
    if (cg >= 64) {
        int c = cg - 64;
        float m = s3[c * 2] / NPIXF;
        float v = s3[c * 2 + 1] / NPIXF - m * m;
        sc = g3[c] * rsqrtf(v + BNEPS);
        bi = be3[c] - m * sc;
    } else {
        int c = cg;
        float m = s4[c * 2] / NPIXF;
        float v = s4[c * 2 + 1] / NPIXF - m * m;
        sc = g4[c] * rsqrtf(v + BNEPS);
        bi = be4[c] - m * sc;
    }
    float4 a = *(float4*)(io + e);
    float4 b = *(float4*)(io + e + 4);
    a.x = fmaxf(0.f, a.x * sc + bi); a.y = fmaxf(0.f, a.y * sc + bi);
    a.z = fmaxf(0.f, a.z * sc + bi); a.w = fmaxf(0.f, a.w * sc + bi);
    b.x = fmaxf(0.f, b.x * sc + bi); b.y = fmaxf(0.f, b.y * sc + bi);
    b.z = fmaxf(0.f, b.z * sc + bi); b.w = fmaxf(0.f, b.w * sc + bi);
    *(float4*)(io + e) = a;
    *(float4*)(io + e + 4) = b;
}

extern "C" void kernel_launch(void* const* d_in, const int* in_sizes, int n_in,
                              void* d_out, int out_size, void* d_ws, size_t ws_size,
                              hipStream_t stream)
{
    const float* x   = (const float*)d_in[0];
    const float* w1  = (const float*)d_in[1];
    const float* b1  = (const float*)d_in[2];
    const float* g1  = (const float*)d_in[3];
    const float* be1 = (const float*)d_in[4];
    const float* w2  = (const float*)d_in[5];
    const float* b2  = (const float*)d_in[6];
    const float* g2  = (const float*)d_in[7];
    const float* be2 = (const float*)d_in[8];
    const float* w3  = (const float*)d_in[9];
    const float* b3  = (const float*)d_in[10];
    const float* be3 = (const float*)d_in[12];
    const float* g3  = (const float*)d_in[11];
    const float* w4  = (const float*)d_in[13];
    const float* b4  = (const float*)d_in[14];
    const float* g4  = (const float*)d_in[15];
    const float* be4 = (const float*)d_in[16];
    (void)in_sizes; (void)n_in; (void)out_size;

    if (ws_size < 4096) return;       // need 1 KB of stats scratch
    float* stats = (float*)d_ws;      // [4][256]: per-stage (sum, sumsq) pairs
    float* F = (float*)d_out;
    u16* c1 = (u16*)d_out;

    hipMemsetAsync(stats, 0, 4096, stream);

    // c1 raw (bf16) -> out ch[0,64) byte-slots; stats1
    k_conv1<<<dim3(400, 8), 256, 0, stream>>>(x, w1, b1, c1, stats);
    // conv2: bf16 c1 with BN1 affine+relu on load -> raw2 f32 in ch[64,128); stats2
    k_conv3<128, true, true><<<dim3(5, 20, 8), 256, 0, stream>>>(
        (const void*)d_out, 256L * HW, w2, b2, stats, g1, be1, F, 128, 64, stats + 256);
    // sobel: BN2+relu(raw2) -> edge f32 in ch[0,64)
    k_sobel<<<dim3(5, 20, 512), 256, 0, stream>>>(F, stats + 256, g2, be2);
    // conv3: edge -> raw c3 in ch[64,128) (overwrites dead raw2); stats3
    k_conv3<64, false, false><<<dim3(5, 20, 8), 256, 0, stream>>>(
        (const void*)F, 128L * HW, w3, b3, nullptr, nullptr, nullptr, F, 128, 64, stats + 512);
    // conv4 (skip): x -> raw in ch[0,64) (overwrites dead edge); stats4
    k_conv3<64, false, false><<<dim3(5, 20, 8), 256, 0, stream>>>(
        (const void*)x, 64L * HW, w4, b4, nullptr, nullptr, nullptr, F, 128, 0, stats + 768);
    // final BN+ReLU in place
    k_bnrelu<<<12800, 256, 0, stream>>>(F, stats + 512, stats + 768, g3, be3, g4, be4);
}

// Round 3
// 1240.305 us; speedup vs baseline: 2.3806x; 2.3806x over previous
//
#include <hip/hip_runtime.h>

typedef unsigned short u16;
typedef unsigned int u32;

#define WD 160
#define HW 25600
#define NPIXF 204800.0f
#define BNEPS 1e-5f

__device__ __forceinline__ float bf2f(u16 u) { return __uint_as_float(((u32)u) << 16); }
__device__ __forceinline__ u16 f2bf(float f) {
    u32 x = __float_as_uint(f);
    return (u16)((x + 0x7FFFu + ((x >> 16) & 1u)) >> 16);
}
__device__ __forceinline__ u32 pack2(float a, float b) {
    return (u32)f2bf(a) | ((u32)f2bf(b) << 16);
}

// Slotted stats: per stage, float[nslot][128][est]; entry (sum, sumsq) at
// ((slot*128 + oc)*est). est=4 pads each pair to 16B (4 pairs per 64B line);
// slots live in distinct cachelines -> per-line atomic chains cut by nslot*2.

// ---------------------------------------------------------------------------
// conv1: 1x1 conv (64 -> 128) + bias. x f32 -> c1 bf16 packed into the byte
// region of d_out ch[0,64) per batch. Accumulates slotted stats (pre-round).
// ---------------------------------------------------------------------------
__global__ __launch_bounds__(256) void k_conv1(
    const float* __restrict__ x, const float* __restrict__ w1,
    const float* __restrict__ bias, u16* __restrict__ c1,
    float* __restrict__ stats, int nslot, int est)
{
    __shared__ __align__(16) float Xs[64][68];
    __shared__ __align__(16) float Ws[64][136];
    const int tid = threadIdx.x;
    const int b = blockIdx.y;
    const int px0 = blockIdx.x * 64;
    const int slot = (blockIdx.y * gridDim.x + blockIdx.x) & (nslot - 1);

    for (int d = tid; d < 8192; d += 256)
        Ws[d & 63][d >> 6] = w1[d];
    for (int d = tid; d < 1024; d += 256) {
        int i = d >> 4, j4 = (d & 15) * 4;
        *(float4*)&Xs[i][j4] = *(const float4*)&x[(size_t)(b * 64 + i) * HW + px0 + j4];
    }
    __syncthreads();

    const int tx = tid & 15, ty = tid >> 4;
    float acc[8][4];
#pragma unroll
    for (int o = 0; o < 8; ++o)
#pragma unroll
        for (int j = 0; j < 4; ++j) acc[o][j] = 0.f;

#pragma unroll 4
    for (int i = 0; i < 64; ++i) {
        const float4 xv = *(const float4*)&Xs[i][tx * 4];
        const float4 w0 = *(const float4*)&Ws[i][ty * 8];
        const float4 wq = *(const float4*)&Ws[i][ty * 8 + 4];
        const float xr[4] = {xv.x, xv.y, xv.z, xv.w};
        const float wv[8] = {w0.x, w0.y, w0.z, w0.w, wq.x, wq.y, wq.z, wq.w};
#pragma unroll
        for (int o = 0; o < 8; ++o)
#pragma unroll
            for (int j = 0; j < 4; ++j)
                acc[o][j] = fmaf(wv[o], xr[j], acc[o][j]);
    }

    u16* outb = c1 + (size_t)b * 256 * HW;
    const int pxb = px0 + tx * 4;
#pragma unroll
    for (int o = 0; o < 8; ++o) {
        const int oc = ty * 8 + o;
        const float bv = bias[oc];
        float v0 = acc[o][0] + bv, v1 = acc[o][1] + bv;
        float v2 = acc[o][2] + bv, v3 = acc[o][3] + bv;
        float s = v0 + v1 + v2 + v3;
        float s2 = v0 * v0 + v1 * v1 + v2 * v2 + v3 * v3;
        uint2 q = make_uint2(pack2(v0, v1), pack2(v2, v3));
        *(uint2*)(outb + (size_t)oc * HW + pxb) = q;
#pragma unroll
        for (int off = 1; off < 16; off <<= 1) {
            s  += __shfl_xor(s, off);
            s2 += __shfl_xor(s2, off);
        }
        if (tx == 0) {
            float* p = stats + ((size_t)slot * 128 + oc) * est;
            atomicAdd(p, s);
            atomicAdd(p + 1, s2);
        }
    }
}

// ---------------------------------------------------------------------------
// generic 3x3 conv (CIN -> 64) + bias -> raw f32 + slotted stats.
// AFF: fold slotted stats_in, apply BN affine + relu on load. BF16IN: input bf16.
// ---------------------------------------------------------------------------
template<int CIN, bool AFF, bool BF16IN>
__global__ __launch_bounds__(256) void k_conv3(
    const void* __restrict__ inv, long bstride,
    const float* __restrict__ w, const float* __restrict__ bias,
    const float* __restrict__ stats_in, const float* __restrict__ g_in,
    const float* __restrict__ be_in,
    float* __restrict__ out, int OUTC, int coff,
    float* __restrict__ stats_out, int nslot, int est)
{
    __shared__ __align__(16) float pat[8][10][36];
    __shared__ __align__(16) float wl[8][9][68];
    __shared__ float asc[CIN];
    __shared__ float abi[CIN];

    const int tid = threadIdx.x;
    const int b = blockIdx.z;
    const int x0 = blockIdx.x * 32, y0 = blockIdx.y * 8;
    const int slot = (blockIdx.x + gridDim.x * (blockIdx.y + gridDim.y * blockIdx.z)) & (nslot - 1);

    if constexpr (AFF) {
        for (int c = tid; c < CIN; c += 256) {
            float sm = 0.f, sq = 0.f;
            for (int s = 0; s < nslot; ++s) {
                const float* p = stats_in + ((size_t)s * 128 + c) * est;
                sm += p[0]; sq += p[1];
            }
            float m = sm / NPIXF;
            float v = sq / NPIXF - m * m;
            float sc = g_in[c] * rsqrtf(v + BNEPS);
            asc[c] = sc;
            abi[c] = be_in[c] - m * sc;
        }
    }

    const int tx = tid & 3, ry = (tid >> 2) & 7, ty = tid >> 5;
    float acc[8][8];
#pragma unroll
    for (int o = 0; o < 8; ++o)
#pragma unroll
        for (int j = 0; j < 8; ++j) acc[o][j] = 0.f;

    for (int icg = 0; icg < CIN / 8; ++icg) {
        __syncthreads();
        for (int d = tid; d < 2720; d += 256) {
            int ic = d / 340, rem = d - ic * 340;
            int r = rem / 34, cc = rem - r * 34;
            int gy = y0 + r - 1, gx = x0 + cc - 1;
            float v = 0.f;
            if ((unsigned)gy < 160u && (unsigned)gx < 160u) {
                int icn = icg * 8 + ic;
                if constexpr (BF16IN)
                    v = bf2f(((const u16*)inv)[(size_t)b * bstride + (size_t)icn * HW + gy * WD + gx]);
                else
                    v = ((const float*)inv)[(size_t)b * bstride + (size_t)icn * HW + gy * WD + gx];
                if constexpr (AFF) v = fmaxf(0.f, v * asc[icn] + abi[icn]);
            }
            pat[ic][r][cc] = v;
        }
        for (int d = tid; d < 4608; d += 256) {
            int oc = d / 72, r = d - oc * 72;
            int ic = r / 9, tap = r - ic * 9;
            wl[ic][tap][oc] = w[(size_t)oc * CIN * 9 + (size_t)icg * 72 + r];
        }
        __syncthreads();

        for (int ic = 0; ic < 8; ++ic) {
#pragma unroll
            for (int dy = 0; dy < 3; ++dy) {
                const float* pr = &pat[ic][ry + dy][tx * 8];
                const float4 xa = *(const float4*)pr;
                const float4 xb = *(const float4*)(pr + 4);
                const float4 xc = *(const float4*)(pr + 8);
                const float xr[12] = {xa.x, xa.y, xa.z, xa.w,
                                      xb.x, xb.y, xb.z, xb.w,
                                      xc.x, xc.y, xc.z, xc.w};
#pragma unroll
                for (int dx = 0; dx < 3; ++dx) {
                    const float4 w0 = *(const float4*)&wl[ic][dy * 3 + dx][ty * 8];
                    const float4 wq = *(const float4*)&wl[ic][dy * 3 + dx][ty * 8 + 4];
                    const float wv[8] = {w0.x, w0.y, w0.z, w0.w, wq.x, wq.y, wq.z, wq.w};
#pragma unroll
                    for (int o = 0; o < 8; ++o)
#pragma unroll
                        for (int j = 0; j < 8; ++j)
                            acc[o][j] = fmaf(wv[o], xr[j + dx], acc[o][j]);
                }
            }
        }
    }

    const int gy = y0 + ry, gx0 = x0 + tx * 8;
    float* obase = out + (size_t)(b * OUTC + coff) * HW + gy * WD + gx0;
#pragma unroll
    for (int o = 0; o < 8; ++o) {
        const int oc = ty * 8 + o;
        const float bv = bias[oc];
        float v[8];
        float s = 0.f, s2 = 0.f;
#pragma unroll
        for (int j = 0; j < 8; ++j) {
            v[j] = acc[o][j] + bv;
            s += v[j];
            s2 += v[j] * v[j];
        }
        *(float4*)(obase + (size_t)oc * HW) = make_float4(v[0], v[1], v[2], v[3]);
        *(float4*)(obase + (size_t)oc * HW + 4) = make_float4(v[4], v[5], v[6], v[7]);
#pragma unroll
        for (int off = 1; off < 32; off <<= 1) {
            s  += __shfl_xor(s, off);
            s2 += __shfl_xor(s2, off);
        }
        if ((tid & 31) == 0) {
            float* p = stats_out + ((size_t)slot * 128 + oc) * est;
            atomicAdd(p, s);
            atomicAdd(p + 1, s2);
        }
    }
}

// ---------------------------------------------------------------------------
// sobel: folds slotted stats2, BN2 affine + relu on load from out ch[64,128),
// writes edge f32 into out ch[0,64). 8 nonzero taps of the combined 5x5.
// ---------------------------------------------------------------------------
__global__ __launch_bounds__(256) void k_sobel(
    float* __restrict__ F, const float* __restrict__ st,
    const float* __restrict__ g, const float* __restrict__ be, int nslot, int est)
{
    const int tid = threadIdx.x;
    const int c = blockIdx.z & 63, b = blockIdx.z >> 6;
    const int x0 = blockIdx.x * 32, y0 = blockIdx.y * 8;
    float sm = 0.f, sq = 0.f;
    for (int s = 0; s < nslot; ++s) {
        const float* p = st + ((size_t)s * 128 + c) * est;
        sm += p[0]; sq += p[1];
    }
    const float m = sm / NPIXF;
    const float var = sq / NPIXF - m * m;
    const float sc = g[c] * rsqrtf(var + BNEPS);
    const float bi = be[c] - m * sc;
    const float* base = F + ((size_t)b * 128 + 64 + c) * HW;
    float* dst = F + ((size_t)b * 128 + c) * HW;
    const int px = tid & 31, ry = tid >> 5;
    const int gx = x0 + px, gy = y0 + ry;
    auto LD = [&](int yy, int xx) -> float {
        if ((unsigned)yy >= 160u || (unsigned)xx >= 160u) return 0.f;
        return fmaxf(0.f, base[yy * WD + xx] * sc + bi);
    };
    float r = 4.f * LD(gy - 1, gx - 1) + 4.f * LD(gy - 1, gx)
            - 2.f * LD(gy, gx - 2) - 8.f * LD(gy, gx - 1)
            + 8.f * LD(gy, gx + 1) + 2.f * LD(gy, gx + 2)
            - 4.f * LD(gy + 1, gx) - 4.f * LD(gy + 1, gx + 1);
    dst[gy * WD + gx] = r;
}

// ---------------------------------------------------------------------------
// fold slotted stats for stages conv3 (s2s) and conv4 (s3s) into f23[256][2]:
// t<128 -> conv3 oc=t; t>=128 -> conv4 oc=t-128.
// ---------------------------------------------------------------------------
__global__ __launch_bounds__(256) void k_fold(
    const float* __restrict__ s2s, const float* __restrict__ s3s,
    float* __restrict__ f23, int nslot, int est)
{
    const int t = threadIdx.x;
    const float* src = (t < 128) ? s2s : s3s;
    const int oc = t & 127;
    float sm = 0.f, sq = 0.f;
    for (int s = 0; s < nslot; ++s) {
        const float* p = src + ((size_t)s * 128 + oc) * est;
        sm += p[0]; sq += p[1];
    }
    f23[t * 2] = sm;
    f23[t * 2 + 1] = sq;
}

// ---------------------------------------------------------------------------
// final in-place BN+ReLU on d_out; reads folded f23.
// ---------------------------------------------------------------------------
__global__ __launch_bounds__(256) void k_bnrelu(
    float* __restrict__ io, const float* __restrict__ f23,
    const float* __restrict__ g3, const float* __restrict__ be3,
    const float* __restrict__ g4, const float* __restrict__ be4)
{
    const size_t e = (size_t)(blockIdx.x * 256 + threadIdx.x) * 8;
    const int cg = (int)((e / HW) & 127);
    float sm, sq, gg, bb;
    if (cg >= 64) {
        int c = cg - 64;
        sm = f23[c * 2]; sq = f23[c * 2 + 1]; gg = g3[c]; bb = be3[c];
    } else {
        sm = f23[(128 + cg) * 2]; sq = f23[(128 + cg) * 2 + 1]; gg = g4[cg]; bb = be4[cg];
    }
    float m = sm / NPIXF;
    float v = sq / NPIXF - m * m;
    float sc = gg * rsqrtf(v + BNEPS);
    float bi = bb - m * sc;
    float4 a = *(float4*)(io + e);
    float4 b = *(float4*)(io + e + 4);
    a.x = fmaxf(0.f, a.x * sc + bi); a.y = fmaxf(0.f, a.y * sc + bi);
    a.z = fmaxf(0.f, a.z * sc + bi); a.w = fmaxf(0.f, a.w * sc + bi);
    b.x = fmaxf(0.f, b.x * sc + bi); b.y = fmaxf(0.f, b.y * sc + bi);
    b.z = fmaxf(0.f, b.z * sc + bi); b.w = fmaxf(0.f, b.w * sc + bi);
    *(float4*)(io + e) = a;
    *(float4*)(io + e + 4) = b;
}

extern "C" void kernel_launch(void* const* d_in, const int* in_sizes, int n_in,
                              void* d_out, int out_size, void* d_ws, size_t ws_size,
                              hipStream_t stream)
{
    const float* x   = (const float*)d_in[0];
    const float* w1  = (const float*)d_in[1];
    const float* b1  = (const float*)d_in[2];
    const float* g1  = (const float*)d_in[3];
    const float* be1 = (const float*)d_in[4];
    const float* w2  = (const float*)d_in[5];
    const float* b2  = (const float*)d_in[6];
    const float* g2  = (const float*)d_in[7];
    const float* be2 = (const float*)d_in[8];
    const float* w3  = (const float*)d_in[9];
    const float* b3  = (const float*)d_in[10];
    const float* g3  = (const float*)d_in[11];
    const float* be3 = (const float*)d_in[12];
    const float* w4  = (const float*)d_in[13];
    const float* b4  = (const float*)d_in[14];
    const float* g4  = (const float*)d_in[15];
    const float* be4 = (const float*)d_in[16];
    (void)in_sizes; (void)n_in; (void)out_size;

    // pick largest nslot (pow2 <= 32) and pair padding that fit ws_size
    int nslot = 32, est = 4;
    auto needed = [&](int ns, int e) -> size_t {
        return ((size_t)4 * ns * 128 * e + 512) * 4;
    };
    while (nslot > 1 && needed(nslot, est) > ws_size) nslot >>= 1;
    if (needed(nslot, est) > ws_size) est = 2;
    if (needed(nslot, est) > ws_size) return;

    float* S = (float*)d_ws;
    const size_t stg = (size_t)nslot * 128 * est;   // floats per stage
    float* S0 = S;                                  // conv1 stats (BN1)
    float* S1 = S0 + stg;                           // conv2 stats (BN2)
    float* S2 = S1 + stg;                           // conv3 stats (BN3)
    float* S3 = S2 + stg;                           // conv4 stats (BN4)
    float* f23 = S3 + stg;                          // folded [256][2]
    float* F = (float*)d_out;
    u16* c1 = (u16*)d_out;

    hipMemsetAsync(S, 0, (4 * stg + 512) * sizeof(float), stream);

    k_conv1<<<dim3(400, 8), 256, 0, stream>>>(x, w1, b1, c1, S0, nslot, est);
    k_conv3<128, true, true><<<dim3(5, 20, 8), 256, 0, stream>>>(
        (const void*)d_out, 256L * HW, w2, b2, S0, g1, be1, F, 128, 64, S1, nslot, est);
    k_sobel<<<dim3(5, 20, 512), 256, 0, stream>>>(F, S1, g2, be2, nslot, est);
    k_conv3<64, false, false><<<dim3(5, 20, 8), 256, 0, stream>>>(
        (const void*)F, 128L * HW, w3, b3, nullptr, nullptr, nullptr, F, 128, 64, S2, nslot, est);
    k_conv3<64, false, false><<<dim3(5, 20, 8), 256, 0, stream>>>(
        (const void*)x, 64L * HW, w4, b4, nullptr, nullptr, nullptr, F, 128, 0, S3, nslot, est);
    k_fold<<<1, 256, 0, stream>>>(S2, S3, f23, nslot, est);
    k_bnrelu<<<12800, 256, 0, stream>>>(F, f23, g3, be3, g4, be4);
}

// Round 5
// 399.015 us; speedup vs baseline: 7.3998x; 3.1084x over previous
//
#include <hip/hip_runtime.h>

typedef unsigned short u16;
typedef unsigned int u32;
typedef __attribute__((ext_vector_type(8))) short bf16x8;
typedef __attribute__((ext_vector_type(4))) float f32x4;

#define WD 160
#define HW 25600
#define NPIXF 204800.0f
#define BNEPS 1e-5f
#define SLOTB 6553600ll      // bytes of one 64ch f32 slot (per batch half)
#define BATB  13107200ll     // bytes per batch in d_out (2 slots)

__device__ __forceinline__ float bf2f(u16 u){ return __uint_as_float(((u32)u)<<16); }
__device__ __forceinline__ u16 f2bf(float f){ u32 x=__float_as_uint(f); return (u16)((x + 0x7FFFu + ((x>>16)&1u))>>16); }
__device__ __forceinline__ u32 pack2(float a,float b){ return (u32)f2bf(a) | ((u32)f2bf(b)<<16); }

__device__ __forceinline__ f32x4 MF(bf16x8 a, bf16x8 b, f32x4 c){
  return __builtin_amdgcn_mfma_f32_16x16x32_bf16(a, b, c, 0, 0, 0);
}
__device__ __forceinline__ void gload16(const void* g, void* l){
  __builtin_amdgcn_global_load_lds((const __attribute__((address_space(1))) void*)(g),
                                   (__attribute__((address_space(3))) void*)(l), 16, 0, 0);
}

// ============================================================================
// weight prep: f32 reference layouts -> packed bf16 MFMA layouts in ws.
// wp1 [icb2][kc4][oc128][i8]                  (B-frag for conv1, no swizzle)
// wp2 [icb4][tap9][kc4][oc64][i8]             (B-frag for conv2, no swizzle)
// wp3/wp4 [icb2][tap9][oc64][k32] oc-swizzled (A-frag for conv3/4)
// ============================================================================
__global__ __launch_bounds__(256) void k_prepw(
    const float* __restrict__ w1, const float* __restrict__ w2,
    const float* __restrict__ w3, const float* __restrict__ w4,
    u16* __restrict__ wp1, u16* __restrict__ wp2,
    u16* __restrict__ wp3, u16* __restrict__ wp4)
{
  int t = blockIdx.x*256 + threadIdx.x;
  if (t < 8192){
    int i = t&7, oc = (t>>3)&127, kc = (t>>10)&3, icb = t>>12;
    wp1[t] = f2bf(w1[oc*64 + icb*32 + kc*8 + i]);
  }
  int u = t - 8192;
  if (u >= 0 && u < 73728){
    int i = u&7, oc = (u>>3)&63, kc = (u>>9)&3, v = u>>11;     // v = icb*9+tap
    int icb = (v*57)>>9; int tap = v - icb*9;
    wp2[u] = f2bf(w2[(oc*128 + icb*32 + kc*8 + i)*9 + tap]);
  }
  int u3 = t - (8192+73728);
  if (u3 >= 0 && u3 < 36864){
    int k = u3&31, oc = (u3>>5)&63, v = u3>>11;                // v = icb*9+tap
    int icb = (v >= 9) ? 1 : 0; int tap = v - icb*9;
    int phys = u3 ^ (((oc>>1)&3)<<3);                          // chunk swizzle (u16 idx)
    wp3[phys] = f2bf(w3[(oc*64 + icb*32 + k)*9 + tap]);
    wp4[phys] = f2bf(w4[(oc*64 + icb*32 + k)*9 + tap]);
  }
}

// ============================================================================
// conv1: 1x1, 64->128, MFMA. x NCHW f32 -> c1raw NHWC bf16 (even slot) + stats.
// Block: 256 flat px, 4 waves; wave: 4 px-tiles x 8 oc-tiles. K=64 (2 icb).
// ============================================================================
__global__ __launch_bounds__(256,2) void k_conv1(
    const float* __restrict__ x, const u16* __restrict__ wp1,
    char* __restrict__ dout, float* __restrict__ stats, int nslot)
{
  __shared__ __align__(16) char Xs[16384];   // [256px][32ic] bf16 swizzled
  __shared__ __align__(16) char Ws[8192];    // [kc4][128oc][8ic]
  const int tid = threadIdx.x, lane = tid&63, w = tid>>6;
  const int l15 = lane&15, kc = lane>>4;
  const int b = blockIdx.y, px0 = blockIdx.x*256;
  const float* xb = x + (size_t)b*64*HW;

  f32x4 acc[4][8];
  for (int t=0;t<4;++t) for (int o=0;o<8;++o) acc[t][o] = (f32x4){0.f,0.f,0.f,0.f};

  int a1off[4];
  for (int t=0;t<4;++t){
    int px = (w*4+t)*16 + l15;
    a1off[t] = px*64 + ((kc ^ ((px>>1)&3))<<4);
  }
  const int wboff = kc*2048 + l15*16;

  for (int icb=0; icb<2; ++icb){
    __syncthreads();
    for (int it=0; it<16; ++it){             // transpose-stage: 4096 b32 writes
      int s = it*256 + tid;
      int icp = s >> 8, px = s & 255;
      const float* p = xb + (size_t)(icb*32 + icp*2)*HW + px0 + px;
      float v0 = p[0], v1 = p[HW];
      int phys = px*64 + (((icp>>2) ^ ((px>>1)&3))<<4) + (icp&3)*4;
      *(u32*)(Xs + phys) = pack2(v0, v1);
    }
    for (int it=0; it<2; ++it){              // W: 512 x 16B  (per-icb block = 4096 u16)
      int s = it*256 + tid;
      gload16(wp1 + (size_t)icb*4096 + s*8, Ws + (it*256 + (tid & ~63))*16);
    }
    asm volatile("s_waitcnt vmcnt(0)" ::: "memory");
    __syncthreads();
    bf16x8 a[4], bv[8];
#pragma unroll
    for (int t=0;t<4;++t) a[t] = *(const bf16x8*)(Xs + a1off[t]);
#pragma unroll
    for (int o=0;o<8;++o) bv[o] = *(const bf16x8*)(Ws + o*256 + wboff);
#pragma unroll
    for (int t=0;t<4;++t)
#pragma unroll
      for (int o=0;o<8;++o)
        acc[t][o] = MF(a[t], bv[o], acc[t][o]);
  }

  u16* c1 = (u16*)(dout + (size_t)b*BATB);   // even slot NHWC [HW][128] bf16
  float sa[8], sq[8];
  for (int o=0;o<8;++o){ sa[o]=0.f; sq[o]=0.f; }
  for (int t=0;t<4;++t){
    int pxb = px0 + (w*4+t)*16 + kc*4;
    for (int o=0;o<8;++o){
      int oc = o*16 + l15;
#pragma unroll
      for (int r=0;r<4;++r){
        float v = acc[t][o][r];
        c1[(size_t)(pxb + r)*128 + oc] = f2bf(v);
        sa[o]+=v; sq[o]+=v*v;
      }
    }
  }
  const int slot = (blockIdx.y*gridDim.x + blockIdx.x) & (nslot-1);
  for (int o=0;o<8;++o){
    float s1_=sa[o], s2_=sq[o];
    s1_+=__shfl_xor(s1_,16); s2_+=__shfl_xor(s2_,16);
    s1_+=__shfl_xor(s1_,32); s2_+=__shfl_xor(s2_,32);
    if (lane < 16){
      float* p = stats + ((size_t)slot*128 + o*16 + l15)*4;
      atomicAdd(p, s1_); atomicAdd(p+1, s2_);
    }
  }
}

// fold slotted stats of one stage -> dst[128][2]
__global__ void k_fold(const float* __restrict__ src, float* __restrict__ dst, int nslot){
  int c = threadIdx.x; if (c >= 128) return;
  float sm=0.f, sq=0.f;
  for (int s=0;s<nslot;++s){ const float* p = src + ((size_t)s*128 + c)*4; sm+=p[0]; sq+=p[1]; }
  dst[c*2] = sm; dst[c*2+1] = sq;
}

// bn1: c1raw (even, NHWC bf16) -> relu(bn1) -> c1a (odd, NHWC bf16)
__global__ __launch_bounds__(256) void k_bn1(
    char* __restrict__ dout, const float* __restrict__ f1,
    const float* __restrict__ g1, const float* __restrict__ be1)
{
  __shared__ float asc[128], abi[128];
  int tid = threadIdx.x;
  if (tid < 128){
    float m = f1[tid*2]/NPIXF;
    float v = f1[tid*2+1]/NPIXF - m*m;
    float sc = g1[tid]*rsqrtf(v + BNEPS);
    asc[tid] = sc; abi[tid] = be1[tid] - m*sc;
  }
  __syncthreads();
  int b = blockIdx.y;
  size_t r = ((size_t)blockIdx.x*256 + tid)*8;       // 0..3,276,799 elems
  int c0 = (int)(r & 127);
  const u16* src = (const u16*)(dout + (size_t)b*BATB) + r;
  u16* dst = (u16*)(dout + (size_t)b*BATB + SLOTB) + r;
  uint4 q = *(const uint4*)src;
  u32 wv[4] = {q.x,q.y,q.z,q.w};
#pragma unroll
  for (int j=0;j<4;++j){
    float lo = bf2f((u16)(wv[j]&0xFFFFu)), hi = bf2f((u16)(wv[j]>>16));
    lo = fmaxf(0.f, lo*asc[c0+2*j]   + abi[c0+2*j]);
    hi = fmaxf(0.f, hi*asc[c0+2*j+1] + abi[c0+2*j+1]);
    wv[j] = pack2(lo, hi);
  }
  *(uint4*)dst = make_uint4(wv[0],wv[1],wv[2],wv[3]);
}

// ============================================================================
// conv2: 3x3, 128->64. c1a (odd NHWC bf16) -> raw2 NHWC bf16 (even-lo) + stats.
// D[px][oc]: A=patches, B=weights. Block 32x8 px, 4 waves: 4 px-tiles x 4 oc.
// ============================================================================
__global__ __launch_bounds__(256,2) void k_conv2(
    char* __restrict__ dout, const u16* __restrict__ wp2,
    float* __restrict__ statsO, const u16* __restrict__ zeros, int nslot)
{
  __shared__ __align__(16) char Xs[24576];   // [10][34][32ic] bf16 swizzled + pad
  __shared__ __align__(16) char Ws[36864];   // [tap9][kc4][oc64][8ic]
  const int tid = threadIdx.x, lane = tid&63, w = tid>>6;
  const int l15 = lane&15, kc = lane>>4;
  const int b = blockIdx.z, gx0 = blockIdx.x*32, gy0 = blockIdx.y*8;
  const u16* c1a = (const u16*)(dout + (size_t)b*BATB + SLOTB);
  u16* raw2 = (u16*)(dout + (size_t)b*BATB);

  f32x4 acc[4][4];
  for (int t=0;t<4;++t) for (int o=0;o<4;++o) acc[t][o] = (f32x4){0.f,0.f,0.f,0.f};

  int xon[2][3];
  for (int h=0;h<2;++h) for (int dx=0;dx<3;++dx){
    int xi = l15 + h*16 + dx;
    xon[h][dx] = xi*64 + ((kc ^ ((xi>>1)&3))<<4);
  }
  const int wboff = kc*1024 + l15*16;

  for (int icb=0; icb<4; ++icb){
    __syncthreads();
    for (int it=0; it<6; ++it){              // X: 1360 real 16B slots (+pad->zeros)
      int s = it*256 + tid;
      int p = s>>2, sub = s&3;
      int yy = (int)(((u32)p*241u)>>13);
      int xi = p - yy*34;
      int gy = gy0 - 1 + yy, gx = gx0 - 1 + xi;
      int c = sub ^ ((xi>>1)&3);
      const u16* src = zeros;
      if (p < 340 && (unsigned)gy < 160u && (unsigned)gx < 160u)
        src = c1a + ((size_t)(gy*WD+gx)*128 + icb*32 + c*8);
      gload16(src, Xs + (it*256 + (tid & ~63))*16);
    }
    for (int it=0; it<9; ++it){              // W: 2304 x 16B
      int s = it*256 + tid;
      gload16(wp2 + (size_t)icb*18432 + s*8, Ws + (it*256 + (tid & ~63))*16);
    }
    asm volatile("s_waitcnt vmcnt(0)" ::: "memory");
    __syncthreads();
#pragma unroll
    for (int tap=0; tap<9; ++tap){
      const int dy = tap/3, dx = tap - dy*3;
      bf16x8 a[4], bv[4];
#pragma unroll
      for (int t=0;t<4;++t)
        a[t] = *(const bf16x8*)(Xs + (2*w + (t>>1) + dy)*2176 + xon[t&1][dx]);
#pragma unroll
      for (int o=0;o<4;++o)
        bv[o] = *(const bf16x8*)(Ws + tap*4096 + o*256 + wboff);
#pragma unroll
      for (int t=0;t<4;++t)
#pragma unroll
        for (int o=0;o<4;++o)
          acc[t][o] = MF(a[t], bv[o], acc[t][o]);
    }
  }

  float sa[4]={0,0,0,0}, sq[4]={0,0,0,0};
  for (int t=0;t<4;++t){
    int gy = gy0 + 2*w + (t>>1);
    int gxb = gx0 + (t&1)*16 + kc*4;
    for (int o=0;o<4;++o){
      int oc = o*16 + l15;
#pragma unroll
      for (int r=0;r<4;++r){
        float v = acc[t][o][r];
        raw2[(size_t)(gy*WD + gxb + r)*64 + oc] = f2bf(v);
        sa[o]+=v; sq[o]+=v*v;
      }
    }
  }
  int slot = (blockIdx.x + 5*(blockIdx.y + 20*blockIdx.z)) & (nslot-1);
  for (int o=0;o<4;++o){
    float s1_=sa[o], s2_=sq[o];
    s1_+=__shfl_xor(s1_,16); s2_+=__shfl_xor(s2_,16);
    s1_+=__shfl_xor(s1_,32); s2_+=__shfl_xor(s2_,32);
    if (lane<16){
      float* p = statsO + ((size_t)slot*128 + o*16 + l15)*4;
      atomicAdd(p,s1_); atomicAdd(p+1,s2_);
    }
  }
}

// sobel: bn2+relu(raw2 NHWC bf16, even-lo) -> edge NHWC bf16 (even-hi). 8 taps.
__global__ __launch_bounds__(256) void k_sobel(
    char* __restrict__ dout, const float* __restrict__ f2,
    const float* __restrict__ g2, const float* __restrict__ be2)
{
  __shared__ float asc[64], abi[64];
  int tid = threadIdx.x;
  if (tid < 64){
    float m = f2[tid*2]/NPIXF, v = f2[tid*2+1]/NPIXF - m*m;
    float sc = g2[tid]*rsqrtf(v+BNEPS);
    asc[tid]=sc; abi[tid]=be2[tid]-m*sc;
  }
  __syncthreads();
  int b = blockIdx.z, cb = blockIdx.y;
  int px = blockIdx.x*256 + tid;
  int y = (int)(((u32)px*52429u)>>23);
  int x = px - y*WD;
  const u16* raw2 = (const u16*)(dout + (size_t)b*BATB);
  u16* edge = (u16*)(dout + (size_t)b*BATB + 3276800);
  float av[8] = {0,0,0,0,0,0,0,0};
  auto TAP = [&](int dy, int dx, float wt){
    int yy = y+dy, xx = x+dx;
    if ((unsigned)yy>=160u || (unsigned)xx>=160u) return;
    uint4 q = *(const uint4*)(raw2 + ((size_t)(yy*WD+xx)*64 + cb*8));
    u32 ww[4] = {q.x,q.y,q.z,q.w};
#pragma unroll
    for (int j=0;j<4;++j){
      float lo = bf2f((u16)(ww[j]&0xFFFFu)), hi = bf2f((u16)(ww[j]>>16));
      lo = fmaxf(0.f, lo*asc[cb*8+2*j]   + abi[cb*8+2*j]);
      hi = fmaxf(0.f, hi*asc[cb*8+2*j+1] + abi[cb*8+2*j+1]);
      av[2*j]   += wt*lo;
      av[2*j+1] += wt*hi;
    }
  };
  TAP(-1,-1,4.f); TAP(-1,0,4.f);
  TAP(0,-2,-2.f); TAP(0,-1,-8.f); TAP(0,1,8.f); TAP(0,2,2.f);
  TAP(1,0,-4.f);  TAP(1,1,-4.f);
  uint4 o;
  o.x = pack2(av[0],av[1]); o.y = pack2(av[2],av[3]);
  o.z = pack2(av[4],av[5]); o.w = pack2(av[6],av[7]);
  *(uint4*)(edge + ((size_t)px*64 + cb*8)) = o;
}

// ============================================================================
// conv3/conv4: 3x3, 64->64, D[oc][px] -> raw f32 NCHW at FINAL slot + stats.
// XIN=false: input edge NHWC bf16 (even-hi) -> odd slot (c3).
// XIN=true : input x NCHW f32 (transpose-staged) -> even slot (skip).
// ============================================================================
template<bool XIN>
__global__ __launch_bounds__(256,2) void k_conv34(
    char* __restrict__ dout, const float* __restrict__ x,
    const u16* __restrict__ wp, float* __restrict__ statsO,
    const u16* __restrict__ zeros, int nslot)
{
  __shared__ __align__(16) char Xs[24576];
  __shared__ __align__(16) char Ws[36864];   // [tap9][oc64][k32] swizzled
  const int tid = threadIdx.x, lane = tid&63, w = tid>>6;
  const int l15 = lane&15, kc = lane>>4;
  const int b = blockIdx.z, gx0 = blockIdx.x*32, gy0 = blockIdx.y*8;
  const float* xb = XIN ? (x + (size_t)b*64*HW) : nullptr;
  const u16* edge = XIN ? nullptr : (const u16*)(dout + (size_t)b*BATB + 3276800);
  float* out = XIN ? (float*)(dout + (size_t)b*BATB)
                   : (float*)(dout + (size_t)b*BATB + SLOTB);

  f32x4 acc[4][4];   // [oc-tile][px-tile]
  for (int m=0;m<4;++m) for (int t=0;t<4;++t) acc[m][t] = (f32x4){0.f,0.f,0.f,0.f};

  int xon[2][3];
  for (int h=0;h<2;++h) for (int dx=0;dx<3;++dx){
    int xi = l15 + h*16 + dx;
    xon[h][dx] = xi*64 + ((kc ^ ((xi>>1)&3))<<4);
  }
  int wko[4];
  for (int m=0;m<4;++m){
    int oc = m*16 + l15;
    wko[m] = oc*64 + ((kc ^ ((oc>>1)&3))<<4);
  }

  for (int icb=0; icb<2; ++icb){
    __syncthreads();
    if (XIN){
      for (int it=0; it<22; ++it){           // 5440 b32 transpose writes
        int s = it*256 + tid; if (s >= 5440) break;
        int yq = (int)(((u32)(s>>5)*965u)>>14);     // s/544
        int rem = s - yq*544;
        int icp = (int)(((u32)rem*241u)>>13);       // rem/34
        int xi = rem - icp*34;
        int gy = gy0-1+yq, gx = gx0-1+xi;
        float v0=0.f, v1=0.f;
        if ((unsigned)gy<160u && (unsigned)gx<160u){
          const float* p = xb + (size_t)(icb*32 + icp*2)*HW + gy*WD + gx;
          v0 = p[0]; v1 = p[HW];
        }
        int phys = (yq*34 + xi)*64 + (((icp>>2) ^ ((xi>>1)&3))<<4) + (icp&3)*4;
        *(u32*)(Xs + phys) = pack2(v0, v1);
      }
    } else {
      for (int it=0; it<6; ++it){
        int s = it*256 + tid;
        int p = s>>2, sub = s&3;
        int yy = (int)(((u32)p*241u)>>13);
        int xi = p - yy*34;
        int gy = gy0-1+yy, gx = gx0-1+xi;
        int c = sub ^ ((xi>>1)&3);
        const u16* src = zeros;
        if (p<340 && (unsigned)gy<160u && (unsigned)gx<160u)
          src = edge + ((size_t)(gy*WD+gx)*64 + icb*32 + c*8);
        gload16(src, Xs + (it*256 + (tid & ~63))*16);
      }
    }
    for (int it=0; it<9; ++it){
      int s = it*256 + tid;
      gload16(wp + (size_t)icb*18432 + s*8, Ws + (it*256 + (tid & ~63))*16);
    }
    asm volatile("s_waitcnt vmcnt(0)" ::: "memory");
    __syncthreads();
#pragma unroll
    for (int tap=0; tap<9; ++tap){
      const int dy = tap/3, dx = tap - dy*3;
      bf16x8 a[4], bv[4];
#pragma unroll
      for (int m=0;m<4;++m) a[m] = *(const bf16x8*)(Ws + tap*4096 + wko[m]);
#pragma unroll
      for (int t=0;t<4;++t) bv[t] = *(const bf16x8*)(Xs + (2*w + (t>>1) + dy)*2176 + xon[t&1][dx]);
#pragma unroll
      for (int m=0;m<4;++m)
#pragma unroll
        for (int t=0;t<4;++t)
          acc[m][t] = MF(a[m], bv[t], acc[m][t]);
    }
  }

  float sa[4][4], sq[4][4];
  for (int m=0;m<4;++m) for (int r=0;r<4;++r){ sa[m][r]=0.f; sq[m][r]=0.f; }
  for (int m=0;m<4;++m){
    for (int t=0;t<4;++t){
      int gy = gy0 + 2*w + (t>>1);
      int gx = gx0 + (t&1)*16 + l15;
#pragma unroll
      for (int r=0;r<4;++r){
        float v = acc[m][t][r];
        out[(size_t)(m*16 + kc*4 + r)*HW + gy*WD + gx] = v;
        sa[m][r]+=v; sq[m][r]+=v*v;
      }
    }
  }
  int slot = (blockIdx.x + 5*(blockIdx.y + 20*blockIdx.z)) & (nslot-1);
  for (int m=0;m<4;++m)
    for (int r=0;r<4;++r){
      float s1_=sa[m][r], s2_=sq[m][r];
      s1_+=__shfl_xor(s1_,1); s2_+=__shfl_xor(s2_,1);
      s1_+=__shfl_xor(s1_,2); s2_+=__shfl_xor(s2_,2);
      s1_+=__shfl_xor(s1_,4); s2_+=__shfl_xor(s2_,4);
      s1_+=__shfl_xor(s1_,8); s2_+=__shfl_xor(s2_,8);
      if (l15==0){
        float* p = statsO + ((size_t)slot*128 + m*16 + kc*4 + r)*4;
        atomicAdd(p,s1_); atomicAdd(p+1,s2_);
      }
    }
}

// final in-place BN+ReLU on d_out NCHW f32: ch<64 -> stats4, ch>=64 -> stats3.
__global__ __launch_bounds__(256) void k_bnrelu(
    float* __restrict__ io, const float* __restrict__ f3, const float* __restrict__ f4,
    const float* __restrict__ g3, const float* __restrict__ be3,
    const float* __restrict__ g4, const float* __restrict__ be4)
{
  size_t e = ((size_t)blockIdx.x*256 + threadIdx.x)*8;
  int cg = (int)((e/HW) & 127);
  float* p = io + (size_t)blockIdx.y*3276800 + e;
  float sm,sq,gg,bb;
  if (cg>=64){ int c=cg-64; sm=f3[c*2]; sq=f3[c*2+1]; gg=g3[c]; bb=be3[c]; }
  else       {             sm=f4[cg*2]; sq=f4[cg*2+1]; gg=g4[cg]; bb=be4[cg]; }
  float m = sm/NPIXF;
  float v = sq/NPIXF - m*m;
  float sc = gg*rsqrtf(v + BNEPS);
  float bi = bb - m*sc;
  float4 a = *(float4*)p;
  float4 bq = *(float4*)(p+4);
  a.x=fmaxf(0.f,a.x*sc+bi); a.y=fmaxf(0.f,a.y*sc+bi);
  a.z=fmaxf(0.f,a.z*sc+bi); a.w=fmaxf(0.f,a.w*sc+bi);
  bq.x=fmaxf(0.f,bq.x*sc+bi); bq.y=fmaxf(0.f,bq.y*sc+bi);
  bq.z=fmaxf(0.f,bq.z*sc+bi); bq.w=fmaxf(0.f,bq.w*sc+bi);
  *(float4*)p = a;
  *(float4*)(p+4) = bq;
}

extern "C" void kernel_launch(void* const* d_in, const int* in_sizes, int n_in,
                              void* d_out, int out_size, void* d_ws, size_t ws_size,
                              hipStream_t stream)
{
  const float* x   = (const float*)d_in[0];
  const float* w1  = (const float*)d_in[1];
  const float* g1  = (const float*)d_in[3];
  const float* be1 = (const float*)d_in[4];
  const float* w2  = (const float*)d_in[5];
  const float* g2  = (const float*)d_in[7];
  const float* be2 = (const float*)d_in[8];
  const float* w3  = (const float*)d_in[9];
  const float* g3  = (const float*)d_in[11];
  const float* be3 = (const float*)d_in[12];
  const float* w4  = (const float*)d_in[13];
  const float* g4  = (const float*)d_in[15];
  const float* be4 = (const float*)d_in[16];
  (void)in_sizes; (void)n_in; (void)out_size;
  // NOTE: biases b1..b4 dropped — BN in training mode is shift-invariant.

  int nslot = 32;
  auto need = [&](int ns)->size_t{
    return (size_t)4*ns*128*4*4 + 4096 + (size_t)(8192+73728+36864+36864)*2 + 256;
  };
  while (nslot > 1 && need(nslot) > ws_size) nslot >>= 1;
  if (need(nslot) > ws_size) return;

  char* ws = (char*)d_ws;
  float* S = (float*)ws;
  size_t stg = (size_t)nslot*128*4;
  float* S0=S, *S1=S+stg, *S2=S+2*stg, *S3=S+3*stg;
  float* F = S + 4*stg;                       // folded [4][128][2]
  u16* wp1 = (u16*)(F + 1024);
  u16* wp2 = wp1 + 8192;
  u16* wp3 = wp2 + 73728;
  u16* wp4 = wp3 + 36864;
  u16* zeros = wp4 + 36864;

  hipMemsetAsync(S, 0, 4*stg*sizeof(float), stream);
  hipMemsetAsync(zeros, 0, 256, stream);

  k_prepw<<<464, 256, 0, stream>>>(w1, w2, w3, w4, wp1, wp2, wp3, wp4);
  k_conv1<<<dim3(100,8), 256, 0, stream>>>(x, wp1, (char*)d_out, S0, nslot);
  k_fold<<<1, 128, 0, stream>>>(S0, F, nslot);
  k_bn1<<<dim3(1600,8), 256, 0, stream>>>((char*)d_out, F, g1, be1);
  k_conv2<<<dim3(5,20,8), 256, 0, stream>>>((char*)d_out, wp2, S1, zeros, nslot);
  k_fold<<<1, 128, 0, stream>>>(S1, F+256, nslot);
  k_sobel<<<dim3(100,8,8), 256, 0, stream>>>((char*)d_out, F+256, g2, be2);
  k_conv34<false><<<dim3(5,20,8), 256, 0, stream>>>((char*)d_out, nullptr, wp3, S2, zeros, nslot);
  k_conv34<true ><<<dim3(5,20,8), 256, 0, stream>>>((char*)d_out, x, wp4, S3, zeros, nslot);
  k_fold<<<1, 128, 0, stream>>>(S2, F+512, nslot);
  k_fold<<<1, 128, 0, stream>>>(S3, F+768, nslot);
  k_bnrelu<<<dim3(1600,8), 256, 0, stream>>>((float*)d_out, F+512, F+768, g3, be3, g4, be4);
}

// Round 6
// 392.405 us; speedup vs baseline: 7.5245x; 1.0168x over previous
//
#include <hip/hip_runtime.h>

typedef unsigned short u16;
typedef unsigned int u32;
typedef __attribute__((ext_vector_type(8))) short bf16x8;
typedef __attribute__((ext_vector_type(4))) float f32x4;

#define WD 160
#define HW 25600
#define NPIXF 204800.0f
#define BNEPS 1e-5f
#define SLOTB 6553600ll      // bytes of one 64ch f32 slot (per batch half)
#define BATB  13107200ll     // bytes per batch in d_out (2 slots)

__device__ __forceinline__ float bf2f(u16 u){ return __uint_as_float(((u32)u)<<16); }
__device__ __forceinline__ u16 f2bf(float f){ u32 x=__float_as_uint(f); return (u16)((x + 0x7FFFu + ((x>>16)&1u))>>16); }
__device__ __forceinline__ u32 pack2(float a,float b){ return (u32)f2bf(a) | ((u32)f2bf(b)<<16); }

__device__ __forceinline__ f32x4 MF(bf16x8 a, bf16x8 b, f32x4 c){
  return __builtin_amdgcn_mfma_f32_16x16x32_bf16(a, b, c, 0, 0, 0);
}
__device__ __forceinline__ void gload16(const void* g, void* l){
  __builtin_amdgcn_global_load_lds((const __attribute__((address_space(1))) void*)(g),
                                   (__attribute__((address_space(3))) void*)(l), 16, 0, 0);
}

// ============================================================================
// weight prep: f32 reference layouts -> packed bf16 MFMA layouts in ws.
// wp1 [icb2][kc4][oc128][i8]        (B-frags for conv1, reg-loaded)
// wp2 [icb4][tap9][kc4][oc64][i8]   (B-frags for conv2, reg-loaded)
// wp3/wp4 [icb2][tap9][oc64][k32]   (A-frags for conv3/4, reg-loaded, NO swizzle)
// ============================================================================
__global__ __launch_bounds__(256) void k_prepw(
    const float* __restrict__ w1, const float* __restrict__ w2,
    const float* __restrict__ w3, const float* __restrict__ w4,
    u16* __restrict__ wp1, u16* __restrict__ wp2,
    u16* __restrict__ wp3, u16* __restrict__ wp4)
{
  int t = blockIdx.x*256 + threadIdx.x;
  if (t < 8192){
    int i = t&7, oc = (t>>3)&127, kc = (t>>10)&3, icb = t>>12;
    wp1[t] = f2bf(w1[oc*64 + icb*32 + kc*8 + i]);
  }
  int u = t - 8192;
  if (u >= 0 && u < 73728){
    int i = u&7, oc = (u>>3)&63, kc = (u>>9)&3, v = u>>11;     // v = icb*9+tap
    int icb = (v*57)>>9; int tap = v - icb*9;
    wp2[u] = f2bf(w2[(oc*128 + icb*32 + kc*8 + i)*9 + tap]);
  }
  int u3 = t - (8192+73728);
  if (u3 >= 0 && u3 < 36864){
    int k = u3&31, oc = (u3>>5)&63, v = u3>>11;                // v = icb*9+tap
    int icb = (v >= 9) ? 1 : 0; int tap = v - icb*9;
    wp3[u3] = f2bf(w3[(oc*64 + icb*32 + k)*9 + tap]);
    wp4[u3] = f2bf(w4[(oc*64 + icb*32 + k)*9 + tap]);
  }
}

// ============================================================================
// conv1: 1x1, 64->128. x NCHW f32 -> c1raw NHWC bf16 (even slot) + stats.
// Block 256 thr / 4 waves; out 128 px x 128 oc; wave: px-half (w&1), oc-half (w>>1).
// Both icb staged upfront; weights reg-loaded.
// ============================================================================
__global__ __launch_bounds__(256,2) void k_conv1(
    const float* __restrict__ x, const u16* __restrict__ wp1,
    char* __restrict__ dout, float* __restrict__ stats, int nslot)
{
  __shared__ __align__(16) char Xs[2][8192];   // [icb][128px][32ic] bf16 swizzled
  const int tid = threadIdx.x, lane = tid&63, w = tid>>6;
  const int l15 = lane&15, kc = lane>>4;
  const int b = blockIdx.y, px0 = blockIdx.x*128;
  const float* xb = x + (size_t)b*64*HW;

#pragma unroll 4
  for (int it=0; it<16; ++it){                 // 4096 b32 transpose writes
    int s = it*256 + tid;
    int icb = s >> 11, sl = s & 2047;
    int icp = sl >> 7, px = sl & 127;
    const float* p = xb + (size_t)(icb*32 + icp*2)*HW + px0 + px;
    float v0 = p[0], v1 = p[HW];
    int phys = px*64 + (((icp>>2) ^ ((px>>1)&3))<<4) + (icp&3)*4;
    *(u32*)(Xs[icb] + phys) = pack2(v0, v1);
  }
  __syncthreads();

  f32x4 acc[4][4];                             // [px-tile][oc-tile]
  for (int t=0;t<4;++t) for (int o=0;o<4;++o) acc[t][o] = (f32x4){0.f,0.f,0.f,0.f};
  const int och = (w>>1)*64;
  int a1off[4];
  for (int t=0;t<4;++t){
    int px = (w&1)*64 + t*16 + l15;
    a1off[t] = px*64 + ((kc ^ ((px>>1)&3))<<4);
  }
#pragma unroll
  for (int icb=0; icb<2; ++icb){
    bf16x8 a[4], bw[4];
#pragma unroll
    for (int t=0;t<4;++t) a[t] = *(const bf16x8*)(Xs[icb] + a1off[t]);
#pragma unroll
    for (int o=0;o<4;++o)
      bw[o] = *(const bf16x8*)(wp1 + ((size_t)(icb*4 + kc)*128 + och + o*16 + l15)*8);
#pragma unroll
    for (int t=0;t<4;++t)
#pragma unroll
      for (int o=0;o<4;++o)
        acc[t][o] = MF(a[t], bw[o], acc[t][o]);
  }

  u16* c1 = (u16*)(dout + (size_t)b*BATB);     // even slot NHWC [HW][128] bf16
  float sa[4]={0,0,0,0}, sq[4]={0,0,0,0};
  for (int t=0;t<4;++t){
    int pxb = px0 + (w&1)*64 + t*16 + kc*4;
    for (int o=0;o<4;++o){
      int oc = och + o*16 + l15;
#pragma unroll
      for (int r=0;r<4;++r){
        float v = acc[t][o][r];
        c1[(size_t)(pxb + r)*128 + oc] = f2bf(v);
        sa[o]+=v; sq[o]+=v*v;
      }
    }
  }
  const int slot = (blockIdx.y*gridDim.x + blockIdx.x) & (nslot-1);
  for (int o=0;o<4;++o){
    float s1_=sa[o], s2_=sq[o];
    s1_+=__shfl_xor(s1_,16); s2_+=__shfl_xor(s2_,16);
    s1_+=__shfl_xor(s1_,32); s2_+=__shfl_xor(s2_,32);
    if (lane < 16){
      float* p = stats + ((size_t)slot*128 + och + o*16 + l15)*4;
      atomicAdd(p, s1_); atomicAdd(p+1, s2_);
    }
  }
}

// fold slotted stats of one stage -> dst[128][2]
__global__ void k_fold(const float* __restrict__ src, float* __restrict__ dst, int nslot){
  int c = threadIdx.x; if (c >= 128) return;
  float sm=0.f, sq=0.f;
  for (int s=0;s<nslot;++s){ const float* p = src + ((size_t)s*128 + c)*4; sm+=p[0]; sq+=p[1]; }
  dst[c*2] = sm; dst[c*2+1] = sq;
}

// bn1: c1raw (even, NHWC bf16) -> relu(bn1) -> c1a (odd, NHWC bf16)
__global__ __launch_bounds__(256) void k_bn1(
    char* __restrict__ dout, const float* __restrict__ f1,
    const float* __restrict__ g1, const float* __restrict__ be1)
{
  __shared__ float asc[128], abi[128];
  int tid = threadIdx.x;
  if (tid < 128){
    float m = f1[tid*2]/NPIXF;
    float v = f1[tid*2+1]/NPIXF - m*m;
    float sc = g1[tid]*rsqrtf(v + BNEPS);
    asc[tid] = sc; abi[tid] = be1[tid] - m*sc;
  }
  __syncthreads();
  int b = blockIdx.y;
  size_t r = ((size_t)blockIdx.x*256 + tid)*8;
  int c0 = (int)(r & 127);
  const u16* src = (const u16*)(dout + (size_t)b*BATB) + r;
  u16* dst = (u16*)(dout + (size_t)b*BATB + SLOTB) + r;
  uint4 q = *(const uint4*)src;
  u32 wv[4] = {q.x,q.y,q.z,q.w};
#pragma unroll
  for (int j=0;j<4;++j){
    float lo = bf2f((u16)(wv[j]&0xFFFFu)), hi = bf2f((u16)(wv[j]>>16));
    lo = fmaxf(0.f, lo*asc[c0+2*j]   + abi[c0+2*j]);
    hi = fmaxf(0.f, hi*asc[c0+2*j+1] + abi[c0+2*j+1]);
    wv[j] = pack2(lo, hi);
  }
  *(uint4*)dst = make_uint4(wv[0],wv[1],wv[2],wv[3]);
}

// ============================================================================
// conv2: 3x3, 128->64. c1a (odd NHWC bf16) -> raw2 NHWC bf16 (even-lo) + stats.
// D[px][oc]. Block 32x8 px, 4 waves. Per icb: stage X (gload16) -> drain ->
// compute 9 taps with weights streamed global->VGPR. LDS 24.6 KB.
// ============================================================================
__global__ __launch_bounds__(256,2) void k_conv2(
    char* __restrict__ dout, const u16* __restrict__ wp2,
    float* __restrict__ statsO, const u16* __restrict__ zeros, int nslot)
{
  __shared__ __align__(16) char Xs[24576];     // [10][34][32ic] bf16 swizzled
  const int tid = threadIdx.x, lane = tid&63, w = tid>>6;
  const int l15 = lane&15, kc = lane>>4;
  const int b = blockIdx.z, gx0 = blockIdx.x*32, gy0 = blockIdx.y*8;
  const u16* c1a = (const u16*)(dout + (size_t)b*BATB + SLOTB);
  u16* raw2 = (u16*)(dout + (size_t)b*BATB);

  f32x4 acc[4][4];
  for (int t=0;t<4;++t) for (int o=0;o<4;++o) acc[t][o] = (f32x4){0.f,0.f,0.f,0.f};

  int xon[2][3];
  for (int h=0;h<2;++h) for (int dx=0;dx<3;++dx){
    int xi = l15 + h*16 + dx;
    xon[h][dx] = xi*64 + ((kc ^ ((xi>>1)&3))<<4);
  }

  for (int icb=0; icb<4; ++icb){
    __syncthreads();                           // protect Xs from prev readers
    for (int it=0; it<6; ++it){                // X: 1360 real 16B slots
      int s = it*256 + tid;
      int p = s>>2, sub = s&3;
      int yy = (int)(((u32)p*241u)>>13);
      int xi = p - yy*34;
      int gy = gy0 - 1 + yy, gx = gx0 - 1 + xi;
      int c = sub ^ ((xi>>1)&3);
      const u16* src = zeros + ((tid&63)<<3);  // distinct 16B per lane
      if (p < 340 && (unsigned)gy < 160u && (unsigned)gx < 160u)
        src = c1a + ((size_t)(gy*WD+gx)*128 + icb*32 + c*8);
      gload16(src, Xs + (it*256 + (tid & ~63))*16);
    }
    asm volatile("s_waitcnt vmcnt(0)" ::: "memory");
    __syncthreads();
#pragma unroll
    for (int tap=0; tap<9; ++tap){
      const int dy = tap/3, dx = tap - dy*3;
      bf16x8 a[4], bw[4];
#pragma unroll
      for (int o=0;o<4;++o)
        bw[o] = *(const bf16x8*)(wp2 + ((size_t)((icb*9 + tap)*4 + kc)*64 + o*16 + l15)*8);
#pragma unroll
      for (int t=0;t<4;++t)
        a[t] = *(const bf16x8*)(Xs + (2*w + (t>>1) + dy)*2176 + xon[t&1][dx]);
#pragma unroll
      for (int t=0;t<4;++t)
#pragma unroll
        for (int o=0;o<4;++o)
          acc[t][o] = MF(a[t], bw[o], acc[t][o]);
    }
  }

  float sa[4]={0,0,0,0}, sq[4]={0,0,0,0};
  for (int t=0;t<4;++t){
    int gy = gy0 + 2*w + (t>>1);
    int gxb = gx0 + (t&1)*16 + kc*4;
    for (int o=0;o<4;++o){
      int oc = o*16 + l15;
#pragma unroll
      for (int r=0;r<4;++r){
        float v = acc[t][o][r];
        raw2[(size_t)(gy*WD + gxb + r)*64 + oc] = f2bf(v);
        sa[o]+=v; sq[o]+=v*v;
      }
    }
  }
  int slot = (blockIdx.x + 5*(blockIdx.y + 20*blockIdx.z)) & (nslot-1);
  for (int o=0;o<4;++o){
    float s1_=sa[o], s2_=sq[o];
    s1_+=__shfl_xor(s1_,16); s2_+=__shfl_xor(s2_,16);
    s1_+=__shfl_xor(s1_,32); s2_+=__shfl_xor(s2_,32);
    if (lane<16){
      float* p = statsO + ((size_t)slot*128 + o*16 + l15)*4;
      atomicAdd(p,s1_); atomicAdd(p+1,s2_);
    }
  }
}

// sobel: bn2+relu(raw2 NHWC bf16, even-lo) -> edge NHWC bf16 (even-hi). 8 taps.
__global__ __launch_bounds__(256) void k_sobel(
    char* __restrict__ dout, const float* __restrict__ f2,
    const float* __restrict__ g2, const float* __restrict__ be2)
{
  __shared__ float asc[64], abi[64];
  int tid = threadIdx.x;
  if (tid < 64){
    float m = f2[tid*2]/NPIXF, v = f2[tid*2+1]/NPIXF - m*m;
    float sc = g2[tid]*rsqrtf(v+BNEPS);
    asc[tid]=sc; abi[tid]=be2[tid]-m*sc;
  }
  __syncthreads();
  int b = blockIdx.z, cb = blockIdx.y;
  int px = blockIdx.x*256 + tid;
  int y = (int)(((u32)px*52429u)>>23);
  int x = px - y*WD;
  const u16* raw2 = (const u16*)(dout + (size_t)b*BATB);
  u16* edge = (u16*)(dout + (size_t)b*BATB + 3276800);
  float av[8] = {0,0,0,0,0,0,0,0};
  auto TAP = [&](int dy, int dx, float wt){
    int yy = y+dy, xx = x+dx;
    if ((unsigned)yy>=160u || (unsigned)xx>=160u) return;
    uint4 q = *(const uint4*)(raw2 + ((size_t)(yy*WD+xx)*64 + cb*8));
    u32 ww[4] = {q.x,q.y,q.z,q.w};
#pragma unroll
    for (int j=0;j<4;++j){
      float lo = bf2f((u16)(ww[j]&0xFFFFu)), hi = bf2f((u16)(ww[j]>>16));
      lo = fmaxf(0.f, lo*asc[cb*8+2*j]   + abi[cb*8+2*j]);
      hi = fmaxf(0.f, hi*asc[cb*8+2*j+1] + abi[cb*8+2*j+1]);
      av[2*j]   += wt*lo;
      av[2*j+1] += wt*hi;
    }
  };
  TAP(-1,-1,4.f); TAP(-1,0,4.f);
  TAP(0,-2,-2.f); TAP(0,-1,-8.f); TAP(0,1,8.f); TAP(0,2,2.f);
  TAP(1,0,-4.f);  TAP(1,1,-4.f);
  uint4 o;
  o.x = pack2(av[0],av[1]); o.y = pack2(av[2],av[3]);
  o.z = pack2(av[4],av[5]); o.w = pack2(av[6],av[7]);
  *(uint4*)(edge + ((size_t)px*64 + cb*8)) = o;
}

// ============================================================================
// conv3+conv4 merged: 3x3, 64->64, D[oc][px], raw f32 NCHW + stats.
// blockIdx.z: b = z>>1, job = z&1. job0: edge(NHWC bf16, even-hi)->odd (c3).
// job1: x(NCHW f32)->even (skip). ALL X staged upfront (both icb), one barrier.
// Weights streamed global->VGPR. LDS 49152.
// ============================================================================
__global__ __launch_bounds__(256,2) void k_conv34(
    char* __restrict__ dout, const float* __restrict__ x,
    const u16* __restrict__ wp3, const u16* __restrict__ wp4,
    float* __restrict__ st3, float* __restrict__ st4,
    const u16* __restrict__ zeros, int nslot)
{
  __shared__ __align__(16) char Xs[49152];     // [icb2][10][34][32ch]
  const int tid = threadIdx.x, lane = tid&63, w = tid>>6;
  const int l15 = lane&15, kc = lane>>4;
  const int bz = blockIdx.z, b = bz>>1, job = bz&1;
  const int gx0 = blockIdx.x*32, gy0 = blockIdx.y*8;
  const u16* wp = job ? wp4 : wp3;
  float* statsO = job ? st4 : st3;
  float* out = job ? (float*)(dout + (size_t)b*BATB)
                   : (float*)(dout + (size_t)b*BATB + SLOTB);

  if (job){                                    // x NCHW f32 transpose-stage, both icb
    const float* xb = x + (size_t)b*64*HW;
#pragma unroll 4
    for (int it=0; it<43; ++it){               // 10880 b32 writes
      int s = it*256 + tid; if (s >= 10880) break;
      int icb = (s >= 5440) ? 1 : 0;
      int sl = s - icb*5440;
      int yq = (int)(((u32)(sl>>5)*965u)>>14);       // sl/544
      int rem = sl - yq*544;
      int icp = (int)(((u32)rem*241u)>>13);          // rem/34
      int xi = rem - icp*34;
      int gy = gy0-1+yq, gx = gx0-1+xi;
      float v0=0.f, v1=0.f;
      if ((unsigned)gy<160u && (unsigned)gx<160u){
        const float* p = xb + (size_t)(icb*32 + icp*2)*HW + gy*WD + gx;
        v0 = p[0]; v1 = p[HW];
      }
      int phys = icb*24576 + (yq*34 + xi)*64 + (((icp>>2) ^ ((xi>>1)&3))<<4) + (icp&3)*4;
      *(u32*)(Xs + phys) = pack2(v0, v1);
    }
  } else {                                     // edge NHWC bf16 gload16, both icb
    const u16* edge = (const u16*)(dout + (size_t)b*BATB + 3276800);
    for (int it=0; it<12; ++it){
      int s = it*256 + tid;
      int icb = s >> 11;                       // 1536 slots per icb... (s>=1536)
      icb = (s >= 1536) ? 1 : 0;
      int sl = s - icb*1536;
      int p = sl>>2, sub = sl&3;
      int yy = (int)(((u32)p*241u)>>13);
      int xi = p - yy*34;
      int gy = gy0-1+yy, gx = gx0-1+xi;
      int c = sub ^ ((xi>>1)&3);
      const u16* src = zeros + ((tid&63)<<3);
      if (p<340 && (unsigned)gy<160u && (unsigned)gx<160u)
        src = edge + ((size_t)(gy*WD+gx)*64 + icb*32 + c*8);
      gload16(src, Xs + (it*256 + (tid & ~63))*16);
    }
    asm volatile("s_waitcnt vmcnt(0)" ::: "memory");
  }
  __syncthreads();

  f32x4 acc[4][4];                             // [oc-tile m][px-tile t]
  for (int m=0;m<4;++m) for (int t=0;t<4;++t) acc[m][t] = (f32x4){0.f,0.f,0.f,0.f};
  int xon[2][3];
  for (int h=0;h<2;++h) for (int dx=0;dx<3;++dx){
    int xi = l15 + h*16 + dx;
    xon[h][dx] = xi*64 + ((kc ^ ((xi>>1)&3))<<4);
  }

#pragma unroll
  for (int icb=0; icb<2; ++icb){
#pragma unroll
    for (int tap=0; tap<9; ++tap){
      const int dy = tap/3, dx = tap - dy*3;
      bf16x8 a[4], bv[4];
#pragma unroll
      for (int m=0;m<4;++m)
        a[m] = *(const bf16x8*)(wp + ((size_t)((icb*9+tap)*64 + m*16 + l15)*32 + kc*8));
#pragma unroll
      for (int t=0;t<4;++t)
        bv[t] = *(const bf16x8*)(Xs + icb*24576 + (2*w + (t>>1) + dy)*2176 + xon[t&1][dx]);
#pragma unroll
      for (int m=0;m<4;++m)
#pragma unroll
        for (int t=0;t<4;++t)
          acc[m][t] = MF(a[m], bv[t], acc[m][t]);
    }
  }

  float sa[4][4], sq[4][4];
  for (int m=0;m<4;++m) for (int r=0;r<4;++r){ sa[m][r]=0.f; sq[m][r]=0.f; }
  for (int m=0;m<4;++m){
    for (int t=0;t<4;++t){
      int gy = gy0 + 2*w + (t>>1);
      int gx = gx0 + (t&1)*16 + l15;
#pragma unroll
      for (int r=0;r<4;++r){
        float v = acc[m][t][r];
        out[(size_t)(m*16 + kc*4 + r)*HW + gy*WD + gx] = v;
        sa[m][r]+=v; sq[m][r]+=v*v;
      }
    }
  }
  int slot = (blockIdx.x + 5*(blockIdx.y + 20*blockIdx.z)) & (nslot-1);
  for (int m=0;m<4;++m)
    for (int r=0;r<4;++r){
      float s1_=sa[m][r], s2_=sq[m][r];
      s1_+=__shfl_xor(s1_,1); s2_+=__shfl_xor(s2_,1);
      s1_+=__shfl_xor(s1_,2); s2_+=__shfl_xor(s2_,2);
      s1_+=__shfl_xor(s1_,4); s2_+=__shfl_xor(s2_,4);
      s1_+=__shfl_xor(s1_,8); s2_+=__shfl_xor(s2_,8);
      if (l15==0){
        float* p = statsO + ((size_t)slot*128 + m*16 + kc*4 + r)*4;
        atomicAdd(p,s1_); atomicAdd(p+1,s2_);
      }
    }
}

// final in-place BN+ReLU on d_out NCHW f32: ch<64 -> stats4, ch>=64 -> stats3.
__global__ __launch_bounds__(256) void k_bnrelu(
    float* __restrict__ io, const float* __restrict__ f3, const float* __restrict__ f4,
    const float* __restrict__ g3, const float* __restrict__ be3,
    const float* __restrict__ g4, const float* __restrict__ be4)
{
  size_t e = ((size_t)blockIdx.x*256 + threadIdx.x)*8;
  int cg = (int)((e/HW) & 127);
  float* p = io + (size_t)blockIdx.y*3276800 + e;
  float sm,sq,gg,bb;
  if (cg>=64){ int c=cg-64; sm=f3[c*2]; sq=f3[c*2+1]; gg=g3[c]; bb=be3[c]; }
  else       {             sm=f4[cg*2]; sq=f4[cg*2+1]; gg=g4[cg]; bb=be4[cg]; }
  float m = sm/NPIXF;
  float v = sq/NPIXF - m*m;
  float sc = gg*rsqrtf(v + BNEPS);
  float bi = bb - m*sc;
  float4 a = *(float4*)p;
  float4 bq = *(float4*)(p+4);
  a.x=fmaxf(0.f,a.x*sc+bi); a.y=fmaxf(0.f,a.y*sc+bi);
  a.z=fmaxf(0.f,a.z*sc+bi); a.w=fmaxf(0.f,a.w*sc+bi);
  bq.x=fmaxf(0.f,bq.x*sc+bi); bq.y=fmaxf(0.f,bq.y*sc+bi);
  bq.z=fmaxf(0.f,bq.z*sc+bi); bq.w=fmaxf(0.f,bq.w*sc+bi);
  *(float4*)p = a;
  *(float4*)(p+4) = bq;
}

extern "C" void kernel_launch(void* const* d_in, const int* in_sizes, int n_in,
                              void* d_out, int out_size, void* d_ws, size_t ws_size,
                              hipStream_t stream)
{
  const float* x   = (const float*)d_in[0];
  const float* w1  = (const float*)d_in[1];
  const float* g1  = (const float*)d_in[3];
  const float* be1 = (const float*)d_in[4];
  const float* w2  = (const float*)d_in[5];
  const float* g2  = (const float*)d_in[7];
  const float* be2 = (const float*)d_in[8];
  const float* w3  = (const float*)d_in[9];
  const float* g3  = (const float*)d_in[11];
  const float* be3 = (const float*)d_in[12];
  const float* w4  = (const float*)d_in[13];
  const float* g4  = (const float*)d_in[15];
  const float* be4 = (const float*)d_in[16];
  (void)in_sizes; (void)n_in; (void)out_size;
  // biases b1..b4 dropped — training-mode BN is shift-invariant.

  int nslot = 32;
  auto need = [&](int ns)->size_t{
    return (size_t)4*ns*128*4*4 + 4096 + (size_t)(8192+73728+36864+36864)*2 + 1024;
  };
  while (nslot > 1 && need(nslot) > ws_size) nslot >>= 1;
  if (need(nslot) > ws_size) return;

  char* ws = (char*)d_ws;
  float* S = (float*)ws;
  size_t stg = (size_t)nslot*128*4;
  float* S0=S, *S1=S+stg, *S2=S+2*stg, *S3=S+3*stg;
  float* F = S + 4*stg;                       // folded [4][128][2]
  u16* wp1 = (u16*)(F + 1024);
  u16* wp2 = wp1 + 8192;
  u16* wp3 = wp2 + 73728;
  u16* wp4 = wp3 + 36864;
  u16* zeros = wp4 + 36864;                   // 1024 B

  hipMemsetAsync(S, 0, 4*stg*sizeof(float), stream);
  hipMemsetAsync(zeros, 0, 1024, stream);

  k_prepw<<<464, 256, 0, stream>>>(w1, w2, w3, w4, wp1, wp2, wp3, wp4);
  k_conv1<<<dim3(200,8), 256, 0, stream>>>(x, wp1, (char*)d_out, S0, nslot);
  k_fold<<<1, 128, 0, stream>>>(S0, F, nslot);
  k_bn1<<<dim3(1600,8), 256, 0, stream>>>((char*)d_out, F, g1, be1);
  k_conv2<<<dim3(5,20,8), 256, 0, stream>>>((char*)d_out, wp2, S1, zeros, nslot);
  k_fold<<<1, 128, 0, stream>>>(S1, F+256, nslot);
  k_sobel<<<dim3(100,8,8), 256, 0, stream>>>((char*)d_out, F+256, g2, be2);
  k_conv34<<<dim3(5,20,16), 256, 0, stream>>>((char*)d_out, x, wp3, wp4, S2, S3, zeros, nslot);
  k_fold<<<1, 128, 0, stream>>>(S2, F+512, nslot);
  k_fold<<<1, 128, 0, stream>>>(S3, F+768, nslot);
  k_bnrelu<<<dim3(1600,8), 256, 0, stream>>>((float*)d_out, F+512, F+768, g3, be3, g4, be4);
}

// Round 7
// 348.323 us; speedup vs baseline: 8.4767x; 1.1266x over previous
//
#include <hip/hip_runtime.h>

typedef unsigned short u16;
typedef unsigned int u32;
typedef __attribute__((ext_vector_type(8))) short bf16x8;
typedef __attribute__((ext_vector_type(4))) float f32x4;

#define WD 160
#define HW 25600
#define NPIXF 204800.0f
#define BNEPS 1e-5f
#define SLOTB 6553600ll      // bytes of one 64ch f32 slot (per batch half)
#define BATB  13107200ll     // bytes per batch in d_out (2 slots)

__device__ __forceinline__ float bf2f(u16 u){ return __uint_as_float(((u32)u)<<16); }
__device__ __forceinline__ u16 f2bf(float f){ u32 x=__float_as_uint(f); return (u16)((x + 0x7FFFu + ((x>>16)&1u))>>16); }
__device__ __forceinline__ u32 pack2(float a,float b){ return (u32)f2bf(a) | ((u32)f2bf(b)<<16); }

__device__ __forceinline__ f32x4 MF(bf16x8 a, bf16x8 b, f32x4 c){
  return __builtin_amdgcn_mfma_f32_16x16x32_bf16(a, b, c, 0, 0, 0);
}
__device__ __forceinline__ void gload16(const void* g, void* l){
  __builtin_amdgcn_global_load_lds((const __attribute__((address_space(1))) void*)(g),
                                   (__attribute__((address_space(3))) void*)(l), 16, 0, 0);
}

// ============================================================================
// weight prep (unchanged layouts):
// wp1 [icb2][kc4][oc128][i8]   wp2 [icb4][tap9][kc4][oc64][i8]
// wp3/wp4 [icb2][tap9][oc64][k32]
// ============================================================================
__global__ __launch_bounds__(256) void k_prepw(
    const float* __restrict__ w1, const float* __restrict__ w2,
    const float* __restrict__ w3, const float* __restrict__ w4,
    u16* __restrict__ wp1, u16* __restrict__ wp2,
    u16* __restrict__ wp3, u16* __restrict__ wp4)
{
  int t = blockIdx.x*256 + threadIdx.x;
  if (t < 8192){
    int i = t&7, oc = (t>>3)&127, kc = (t>>10)&3, icb = t>>12;
    wp1[t] = f2bf(w1[oc*64 + icb*32 + kc*8 + i]);
  }
  int u = t - 8192;
  if (u >= 0 && u < 73728){
    int i = u&7, oc = (u>>3)&63, kc = (u>>9)&3, v = u>>11;
    int icb = (v*57)>>9; int tap = v - icb*9;
    wp2[u] = f2bf(w2[(oc*128 + icb*32 + kc*8 + i)*9 + tap]);
  }
  int u3 = t - (8192+73728);
  if (u3 >= 0 && u3 < 36864){
    int k = u3&31, oc = (u3>>5)&63, v = u3>>11;
    int icb = (v >= 9) ? 1 : 0; int tap = v - icb*9;
    wp3[u3] = f2bf(w3[(oc*64 + icb*32 + k)*9 + tap]);
    wp4[u3] = f2bf(w4[(oc*64 + icb*32 + k)*9 + tap]);
  }
}

// ============================================================================
// conv1: 1x1, 64->128. x NCHW f32 -> c1raw NHWC bf16 (even slot) + stats.
// float4 transpose-staging (8 float4 loads/thread).
// ============================================================================
__global__ __launch_bounds__(256,2) void k_conv1(
    const float* __restrict__ x, const u16* __restrict__ wp1,
    char* __restrict__ dout, float* __restrict__ stats, int nslot)
{
  __shared__ __align__(16) char Xs[16384];   // [icb2][128px][32ic] bf16 swizzled
  const int tid = threadIdx.x, lane = tid&63, w = tid>>6;
  const int l15 = lane&15, kc = lane>>4;
  const int b = blockIdx.y, px0 = blockIdx.x*128;
  const float* xb = x + (size_t)b*64*HW;

#pragma unroll
  for (int q=0; q<4; ++q){                   // 1024 tasks: icb2 x cp16 x px4(32)
    int s = q*256 + tid;
    int icb = s >> 9, sl = s & 511;
    int cp = sl >> 5, px4 = sl & 31;
    const float* pa = xb + (size_t)(icb*32 + cp*2)*HW + px0 + px4*4;
    float4 va = *(const float4*)pa;
    float4 vb = *(const float4*)(pa + HW);
    float fa[4] = {va.x, va.y, va.z, va.w};
    float fb[4] = {vb.x, vb.y, vb.z, vb.w};
#pragma unroll
    for (int e=0;e<4;++e){
      int px = px4*4+e;
      int phys = icb*8192 + px*64 + (((cp>>2) ^ ((px>>1)&3))<<4) + (cp&3)*4;
      *(u32*)(Xs + phys) = pack2(fa[e], fb[e]);
    }
  }
  __syncthreads();

  f32x4 acc[4][4];                           // [px-tile][oc-tile]
  for (int t=0;t<4;++t) for (int o=0;o<4;++o) acc[t][o] = (f32x4){0.f,0.f,0.f,0.f};
  const int och = (w>>1)*64;
  int a1off[4];
  for (int t=0;t<4;++t){
    int px = (w&1)*64 + t*16 + l15;
    a1off[t] = px*64 + ((kc ^ ((px>>1)&3))<<4);
  }
#pragma unroll
  for (int icb=0; icb<2; ++icb){
    bf16x8 a[4], bw[4];
#pragma unroll
    for (int t=0;t<4;++t) a[t] = *(const bf16x8*)(Xs + icb*8192 + a1off[t]);
#pragma unroll
    for (int o=0;o<4;++o)
      bw[o] = *(const bf16x8*)(wp1 + ((size_t)(icb*4 + kc)*128 + och + o*16 + l15)*8);
#pragma unroll
    for (int t=0;t<4;++t)
#pragma unroll
      for (int o=0;o<4;++o)
        acc[t][o] = MF(a[t], bw[o], acc[t][o]);
  }

  u16* c1 = (u16*)(dout + (size_t)b*BATB);   // even slot NHWC [HW][128] bf16
  float sa[4]={0,0,0,0}, sq[4]={0,0,0,0};
  for (int t=0;t<4;++t){
    int pxb = px0 + (w&1)*64 + t*16 + kc*4;
    for (int o=0;o<4;++o){
      int oc = och + o*16 + l15;
#pragma unroll
      for (int r=0;r<4;++r){
        float v = acc[t][o][r];
        c1[(size_t)(pxb + r)*128 + oc] = f2bf(v);
        sa[o]+=v; sq[o]+=v*v;
      }
    }
  }
  const int slot = (blockIdx.y*gridDim.x + blockIdx.x) & (nslot-1);
  for (int o=0;o<4;++o){
    float s1_=sa[o], s2_=sq[o];
    s1_+=__shfl_xor(s1_,16); s2_+=__shfl_xor(s2_,16);
    s1_+=__shfl_xor(s1_,32); s2_+=__shfl_xor(s2_,32);
    if (lane < 16){
      float* p = stats + ((size_t)slot*128 + och + o*16 + l15)*4;
      atomicAdd(p, s1_); atomicAdd(p+1, s2_);
    }
  }
}

// fold slotted stats of one stage -> dst[128][2]
__global__ void k_fold(const float* __restrict__ src, float* __restrict__ dst, int nslot){
  int c = threadIdx.x; if (c >= 128) return;
  float sm=0.f, sq=0.f;
  for (int s=0;s<nslot;++s){ const float* p = src + ((size_t)s*128 + c)*4; sm+=p[0]; sq+=p[1]; }
  dst[c*2] = sm; dst[c*2+1] = sq;
}

// fold S2 (t<128) and S3 (t>=128) -> f23[256][2]
__global__ void k_fold23(const float* __restrict__ s2, const float* __restrict__ s3,
                         float* __restrict__ f23, int nslot){
  int t = threadIdx.x;
  const float* src = (t < 128) ? s2 : s3;
  int c = t & 127;
  float sm=0.f, sq=0.f;
  for (int s=0;s<nslot;++s){ const float* p = src + ((size_t)s*128 + c)*4; sm+=p[0]; sq+=p[1]; }
  f23[t*2] = sm; f23[t*2+1] = sq;
}

// ============================================================================
// conv2: 3x3, 128->64. Reads c1raw (even, NHWC bf16), applies BN1 affine+relu
// in REGISTER staging, computes MFMA, writes raw2 bf16 NHWC -> odd-lo + stats.
// ============================================================================
__global__ __launch_bounds__(256,2) void k_conv2(
    char* __restrict__ dout, const u16* __restrict__ wp2,
    const float* __restrict__ f0, const float* __restrict__ g1,
    const float* __restrict__ be1,
    float* __restrict__ statsO, int nslot)
{
  __shared__ __align__(16) char Xs[21760];     // [10][34][32ic] bf16 swizzled
  __shared__ __align__(16) float scbi[128][2]; // (asc, abi) per ch
  const int tid = threadIdx.x, lane = tid&63, w = tid>>6;
  const int l15 = lane&15, kc = lane>>4;
  const int b = blockIdx.z, gx0 = blockIdx.x*32, gy0 = blockIdx.y*8;
  const u16* c1raw = (const u16*)(dout + (size_t)b*BATB);
  u16* raw2 = (u16*)(dout + (size_t)b*BATB + SLOTB);

  if (tid < 128){
    float m = f0[tid*2]/NPIXF;
    float v = f0[tid*2+1]/NPIXF - m*m;
    float sc = g1[tid]*rsqrtf(v + BNEPS);
    scbi[tid][0] = sc; scbi[tid][1] = be1[tid] - m*sc;
  }

  f32x4 acc[4][4];
  for (int t=0;t<4;++t) for (int o=0;o<4;++o) acc[t][o] = (f32x4){0.f,0.f,0.f,0.f};

  int xon[2][3];
  for (int h=0;h<2;++h) for (int dx=0;dx<3;++dx){
    int xi = l15 + h*16 + dx;
    xon[h][dx] = xi*64 + ((kc ^ ((xi>>1)&3))<<4);
  }

  __syncthreads();                             // scbi ready
  for (int icb=0; icb<4; ++icb){
    if (icb) __syncthreads();                  // WAR on Xs
    for (int s = tid; s < 1360; s += 256){     // register staging + BN1 + relu
      int p = s>>2, sub = s&3;
      int yy = (int)(((u32)p*241u)>>13);
      int xi = p - yy*34;
      int gy = gy0 - 1 + yy, gx = gx0 - 1 + xi;
      int c = sub ^ ((xi>>1)&3);               // source ch-chunk
      uint4 o4 = make_uint4(0,0,0,0);
      if ((unsigned)gy < 160u && (unsigned)gx < 160u){
        int cb = icb*32 + c*8;
        uint4 q = *(const uint4*)(c1raw + ((size_t)(gy*WD+gx)*128 + cb));
        u32 ww[4] = {q.x,q.y,q.z,q.w};
        u32 ro[4];
#pragma unroll
        for (int j=0;j<4;++j){
          float lo = bf2f((u16)(ww[j]&0xFFFFu)), hi = bf2f((u16)(ww[j]>>16));
          lo = fmaxf(0.f, lo*scbi[cb+2*j][0]   + scbi[cb+2*j][1]);
          hi = fmaxf(0.f, hi*scbi[cb+2*j+1][0] + scbi[cb+2*j+1][1]);
          ro[j] = pack2(lo, hi);
        }
        o4 = make_uint4(ro[0],ro[1],ro[2],ro[3]);
      }
      *(uint4*)(Xs + p*64 + sub*16) = o4;      // chunk c lands at slot sub = c^swz
    }
    __syncthreads();
#pragma unroll
    for (int tap=0; tap<9; ++tap){
      const int dy = tap/3, dx = tap - dy*3;
      bf16x8 a[4], bw[4];
#pragma unroll
      for (int o=0;o<4;++o)
        bw[o] = *(const bf16x8*)(wp2 + ((size_t)((icb*9 + tap)*4 + kc)*64 + o*16 + l15)*8);
#pragma unroll
      for (int t=0;t<4;++t)
        a[t] = *(const bf16x8*)(Xs + (2*w + (t>>1) + dy)*2176 + xon[t&1][dx]);
#pragma unroll
      for (int t=0;t<4;++t)
#pragma unroll
        for (int o=0;o<4;++o)
          acc[t][o] = MF(a[t], bw[o], acc[t][o]);
    }
  }

  float sa[4]={0,0,0,0}, sq[4]={0,0,0,0};
  for (int t=0;t<4;++t){
    int gy = gy0 + 2*w + (t>>1);
    int gxb = gx0 + (t&1)*16 + kc*4;
    for (int o=0;o<4;++o){
      int oc = o*16 + l15;
#pragma unroll
      for (int r=0;r<4;++r){
        float v = acc[t][o][r];
        raw2[(size_t)(gy*WD + gxb + r)*64 + oc] = f2bf(v);
        sa[o]+=v; sq[o]+=v*v;
      }
    }
  }
  int slot = (blockIdx.x + 5*(blockIdx.y + 20*blockIdx.z)) & (nslot-1);
  for (int o=0;o<4;++o){
    float s1_=sa[o], s2_=sq[o];
    s1_+=__shfl_xor(s1_,16); s2_+=__shfl_xor(s2_,16);
    s1_+=__shfl_xor(s1_,32); s2_+=__shfl_xor(s2_,32);
    if (lane<16){
      float* p = statsO + ((size_t)slot*128 + o*16 + l15)*4;
      atomicAdd(p,s1_); atomicAdd(p+1,s2_);
    }
  }
}

// ============================================================================
// sobel: inline-folds S1, bn2+relu(raw2 odd-lo) -> edge bf16 NHWC (edge_base).
// ============================================================================
__global__ __launch_bounds__(256) void k_sobel(
    char* __restrict__ dout, const float* __restrict__ S1,
    const float* __restrict__ g2, const float* __restrict__ be2,
    u16* __restrict__ edge_base, long ebstride, int nslot)
{
  __shared__ float ascS[8], abiS[8];
  int tid = threadIdx.x;
  int b = blockIdx.z, cb = blockIdx.y;
  if (tid < 64){
    int c = cb*8 + (tid&7);
    float sm=0.f, sq=0.f;
    for (int s = tid>>3; s < nslot; s += 8){
      const float* p = S1 + ((size_t)s*128 + c)*4;
      sm += p[0]; sq += p[1];
    }
    sm += __shfl_xor(sm, 8);  sq += __shfl_xor(sq, 8);
    sm += __shfl_xor(sm, 16); sq += __shfl_xor(sq, 16);
    sm += __shfl_xor(sm, 32); sq += __shfl_xor(sq, 32);
    if (tid < 8){
      float m = sm/NPIXF, v = sq/NPIXF - m*m;
      float sc = g2[c]*rsqrtf(v+BNEPS);
      ascS[tid] = sc; abiS[tid] = be2[c] - m*sc;
    }
  }
  __syncthreads();
  int px = blockIdx.x*256 + tid;
  int y = (int)(((u32)px*52429u)>>23);
  int x = px - y*WD;
  const u16* raw2 = (const u16*)(dout + (size_t)b*BATB + SLOTB);
  u16* edge = edge_base + (size_t)b*ebstride;
  float av[8] = {0,0,0,0,0,0,0,0};
  auto TAP = [&](int dy, int dx, float wt){
    int yy = y+dy, xx = x+dx;
    if ((unsigned)yy>=160u || (unsigned)xx>=160u) return;
    uint4 q = *(const uint4*)(raw2 + ((size_t)(yy*WD+xx)*64 + cb*8));
    u32 ww[4] = {q.x,q.y,q.z,q.w};
#pragma unroll
    for (int j=0;j<4;++j){
      float lo = bf2f((u16)(ww[j]&0xFFFFu)), hi = bf2f((u16)(ww[j]>>16));
      lo = fmaxf(0.f, lo*ascS[2*j]   + abiS[2*j]);
      hi = fmaxf(0.f, hi*ascS[2*j+1] + abiS[2*j+1]);
      av[2*j]   += wt*lo;
      av[2*j+1] += wt*hi;
    }
  };
  TAP(-1,-1,4.f); TAP(-1,0,4.f);
  TAP(0,-2,-2.f); TAP(0,-1,-8.f); TAP(0,1,8.f); TAP(0,2,2.f);
  TAP(1,0,-4.f);  TAP(1,1,-4.f);
  uint4 o;
  o.x = pack2(av[0],av[1]); o.y = pack2(av[2],av[3]);
  o.z = pack2(av[4],av[5]); o.w = pack2(av[6],av[7]);
  *(uint4*)(edge + ((size_t)px*64 + cb*8)) = o;
}

// ============================================================================
// conv3/conv4: 3x3, 64->64, D[oc][px], raw f32 NCHW + stats. Per-icb phases,
// LDS 24.6KB. mode: 2 = merged (z: b=z>>1, job=z&1); 0/1 = single job, b=z.
// job0 (c3): edge NHWC bf16 (gload16) -> odd slot, stats st3.
// job1 (skip): x NCHW f32 float4 transpose-stage -> even slot, stats st4.
// ============================================================================
__global__ __launch_bounds__(256,2) void k_conv34(
    char* __restrict__ dout, const float* __restrict__ x,
    const u16* __restrict__ wp3, const u16* __restrict__ wp4,
    float* __restrict__ st3, float* __restrict__ st4,
    const u16* __restrict__ zeros, const u16* __restrict__ edge_base,
    long ebstride, int nslot, int mode)
{
  __shared__ __align__(16) char Xs[24576];     // [10][34][32ch] + gload pad
  const int tid = threadIdx.x, lane = tid&63, w = tid>>6;
  const int l15 = lane&15, kc = lane>>4;
  int b, job;
  if (mode == 2){ b = blockIdx.z>>1; job = blockIdx.z&1; }
  else          { b = blockIdx.z;    job = mode; }
  const int gx0 = blockIdx.x*32, gy0 = blockIdx.y*8;
  const u16* wp = job ? wp4 : wp3;
  float* statsO = job ? st4 : st3;
  float* out = job ? (float*)(dout + (size_t)b*BATB)
                   : (float*)(dout + (size_t)b*BATB + SLOTB);
  const float* xb = x + (size_t)b*64*HW;
  const u16* edge = edge_base + (size_t)b*ebstride;

  f32x4 acc[4][4];                             // [oc-tile m][px-tile t]
  for (int m=0;m<4;++m) for (int t=0;t<4;++t) acc[m][t] = (f32x4){0.f,0.f,0.f,0.f};
  int xon[2][3];
  for (int h=0;h<2;++h) for (int dx=0;dx<3;++dx){
    int xi = l15 + h*16 + dx;
    xon[h][dx] = xi*64 + ((kc ^ ((xi>>1)&3))<<4);
  }

  for (int icb=0; icb<2; ++icb){
    if (icb) __syncthreads();                  // WAR on Xs
    if (job){
      // x f32 -> bf16 transpose-stage, float4 over aligned gx quads.
      for (int s = tid; s < 1600; s += 256){   // cp16 x yq10 x q10
        int s10 = (int)(((u32)s*6554u)>>16);   // s/10
        int q = s - s10*10;
        int cp = (int)(((u32)s10*6554u)>>16);  // s10/10
        int yq = s10 - cp*10;
        int gy = gy0 - 1 + yq;
        int gxq = gx0 - 4 + q*4;               // 16B-aligned (gx0 mult of 32)
        float fa[4] = {0,0,0,0}, fb[4] = {0,0,0,0};
        if ((unsigned)gy < 160u){
          const float* pa = xb + (size_t)(icb*32 + cp*2)*HW + gy*WD + gxq;
          if (gxq >= 0 && gxq + 3 < 160){
            float4 va = *(const float4*)pa;
            float4 vb = *(const float4*)(pa + HW);
            fa[0]=va.x; fa[1]=va.y; fa[2]=va.z; fa[3]=va.w;
            fb[0]=vb.x; fb[1]=vb.y; fb[2]=vb.z; fb[3]=vb.w;
          } else {
#pragma unroll
            for (int e=0;e<4;++e){
              int gx = gxq + e;
              if ((unsigned)gx < 160u){ fa[e] = pa[e]; fb[e] = pa[e + HW]; }
            }
          }
        }
#pragma unroll
        for (int e=0;e<4;++e){
          int xi = gxq + e - (gx0 - 1);
          if ((unsigned)xi < 34u){
            int phys = (yq*34 + xi)*64 + (((cp>>2) ^ ((xi>>1)&3))<<4) + (cp&3)*4;
            *(u32*)(Xs + phys) = pack2(fa[e], fb[e]);
          }
        }
      }
    } else {
      // edge NHWC bf16 via gload16 (1536 slots incl. zero-pad tail)
      for (int it=0; it<6; ++it){
        int s = it*256 + tid;
        int p = s>>2, sub = s&3;
        int yy = (int)(((u32)p*241u)>>13);
        int xi = p - yy*34;
        int gy = gy0-1+yy, gx = gx0-1+xi;
        int c = sub ^ ((xi>>1)&3);
        const u16* src = zeros + ((tid&63)<<3);
        if (p<340 && (unsigned)gy<160u && (unsigned)gx<160u)
          src = edge + ((size_t)(gy*WD+gx)*64 + icb*32 + c*8);
        gload16(src, Xs + (it*256 + (tid & ~63))*16);
      }
      asm volatile("s_waitcnt vmcnt(0)" ::: "memory");
    }
    __syncthreads();

#pragma unroll
    for (int tap=0; tap<9; ++tap){
      const int dy = tap/3, dx = tap - dy*3;
      bf16x8 a[4], bv[4];
#pragma unroll
      for (int m=0;m<4;++m)
        a[m] = *(const bf16x8*)(wp + ((size_t)((icb*9+tap)*64 + m*16 + l15)*32 + kc*8));
#pragma unroll
      for (int t=0;t<4;++t)
        bv[t] = *(const bf16x8*)(Xs + (2*w + (t>>1) + dy)*2176 + xon[t&1][dx]);
#pragma unroll
      for (int m=0;m<4;++m)
#pragma unroll
        for (int t=0;t<4;++t)
          acc[m][t] = MF(a[m], bv[t], acc[m][t]);
    }
  }

  float sa[4][4], sq[4][4];
  for (int m=0;m<4;++m) for (int r=0;r<4;++r){ sa[m][r]=0.f; sq[m][r]=0.f; }
  for (int m=0;m<4;++m){
    for (int t=0;t<4;++t){
      int gy = gy0 + 2*w + (t>>1);
      int gx = gx0 + (t&1)*16 + l15;
#pragma unroll
      for (int r=0;r<4;++r){
        float v = acc[m][t][r];
        out[(size_t)(m*16 + kc*4 + r)*HW + gy*WD + gx] = v;
        sa[m][r]+=v; sq[m][r]+=v*v;
      }
    }
  }
  int slot = (blockIdx.x + 5*(blockIdx.y + 20*blockIdx.z)) & (nslot-1);
  for (int m=0;m<4;++m)
    for (int r=0;r<4;++r){
      float s1_=sa[m][r], s2_=sq[m][r];
      s1_+=__shfl_xor(s1_,1); s2_+=__shfl_xor(s2_,1);
      s1_+=__shfl_xor(s1_,2); s2_+=__shfl_xor(s2_,2);
      s1_+=__shfl_xor(s1_,4); s2_+=__shfl_xor(s2_,4);
      s1_+=__shfl_xor(s1_,8); s2_+=__shfl_xor(s2_,8);
      if (l15==0){
        float* p = statsO + ((size_t)slot*128 + m*16 + kc*4 + r)*4;
        atomicAdd(p,s1_); atomicAdd(p+1,s2_);
      }
    }
}

// final in-place BN+ReLU on d_out NCHW f32: ch<64 -> stats4, ch>=64 -> stats3.
__global__ __launch_bounds__(256) void k_bnrelu(
    float* __restrict__ io, const float* __restrict__ f23,
    const float* __restrict__ g3, const float* __restrict__ be3,
    const float* __restrict__ g4, const float* __restrict__ be4)
{
  size_t e = ((size_t)blockIdx.x*256 + threadIdx.x)*8;
  int cg = (int)((e/HW) & 127);
  float* p = io + (size_t)blockIdx.y*3276800 + e;
  float sm,sq,gg,bb;
  if (cg>=64){ int c=cg-64; sm=f23[c*2]; sq=f23[c*2+1]; gg=g3[c]; bb=be3[c]; }
  else       { sm=f23[(128+cg)*2]; sq=f23[(128+cg)*2+1]; gg=g4[cg]; bb=be4[cg]; }
  float m = sm/NPIXF;
  float v = sq/NPIXF - m*m;
  float sc = gg*rsqrtf(v + BNEPS);
  float bi = bb - m*sc;
  float4 a = *(float4*)p;
  float4 bq = *(float4*)(p+4);
  a.x=fmaxf(0.f,a.x*sc+bi); a.y=fmaxf(0.f,a.y*sc+bi);
  a.z=fmaxf(0.f,a.z*sc+bi); a.w=fmaxf(0.f,a.w*sc+bi);
  bq.x=fmaxf(0.f,bq.x*sc+bi); bq.y=fmaxf(0.f,bq.y*sc+bi);
  bq.z=fmaxf(0.f,bq.z*sc+bi); bq.w=fmaxf(0.f,bq.w*sc+bi);
  *(float4*)p = a;
  *(float4*)(p+4) = bq;
}

extern "C" void kernel_launch(void* const* d_in, const int* in_sizes, int n_in,
                              void* d_out, int out_size, void* d_ws, size_t ws_size,
                              hipStream_t stream)
{
  const float* x   = (const float*)d_in[0];
  const float* w1  = (const float*)d_in[1];
  const float* g1  = (const float*)d_in[3];
  const float* be1 = (const float*)d_in[4];
  const float* w2  = (const float*)d_in[5];
  const float* g2  = (const float*)d_in[7];
  const float* be2 = (const float*)d_in[8];
  const float* w3  = (const float*)d_in[9];
  const float* g3  = (const float*)d_in[11];
  const float* be3 = (const float*)d_in[12];
  const float* w4  = (const float*)d_in[13];
  const float* g4  = (const float*)d_in[15];
  const float* be4 = (const float*)d_in[16];
  (void)in_sizes; (void)n_in; (void)out_size;
  // biases b1..b4 dropped — training-mode BN is shift-invariant.

  int nslot = 32;
  auto need = [&](int ns)->size_t{
    return (size_t)4*ns*128*4*4 + 4096 + (size_t)(8192+73728+36864+36864)*2 + 1024;
  };
  while (nslot > 1 && need(nslot) > ws_size) nslot >>= 1;
  if (need(nslot) > ws_size) return;

  char* ws = (char*)d_ws;
  float* S = (float*)ws;
  size_t stg = (size_t)nslot*128*4;
  float* S0=S, *S1=S+stg, *S2=S+2*stg, *S3=S+3*stg;
  float* F = S + 4*stg;                        // F0[256] then F23[512]
  u16* wp1 = (u16*)(F + 1024);
  u16* wp2 = wp1 + 8192;
  u16* wp3 = wp2 + 73728;
  u16* wp4 = wp3 + 36864;
  u16* zeros = wp4 + 36864;                    // 1024 B
  size_t base = need(nslot);
  bool big = (ws_size >= base + 26214400ull);
  u16* edge_base;
  long ebstride;
  if (big){ edge_base = (u16*)(ws + base); ebstride = 64L*HW; }       // ws edge
  else    { edge_base = (u16*)((char*)d_out + 3276800); ebstride = BATB/2; } // even-hi

  hipMemsetAsync(S, 0, 4*stg*sizeof(float), stream);
  hipMemsetAsync(zeros, 0, 1024, stream);

  k_prepw<<<464, 256, 0, stream>>>(w1, w2, w3, w4, wp1, wp2, wp3, wp4);
  k_conv1<<<dim3(200,8), 256, 0, stream>>>(x, wp1, (char*)d_out, S0, nslot);
  k_fold<<<1, 128, 0, stream>>>(S0, F, nslot);
  k_conv2<<<dim3(5,20,8), 256, 0, stream>>>((char*)d_out, wp2, F, g1, be1, S1, nslot);
  k_sobel<<<dim3(100,8,8), 256, 0, stream>>>((char*)d_out, S1, g2, be2, edge_base, ebstride, nslot);
  if (big){
    k_conv34<<<dim3(5,20,16), 256, 0, stream>>>((char*)d_out, x, wp3, wp4, S2, S3,
                                                zeros, edge_base, ebstride, nslot, 2);
  } else {
    k_conv34<<<dim3(5,20,8), 256, 0, stream>>>((char*)d_out, x, wp3, wp4, S2, S3,
                                               zeros, edge_base, ebstride, nslot, 0);
    k_conv34<<<dim3(5,20,8), 256, 0, stream>>>((char*)d_out, x, wp3, wp4, S2, S3,
                                               zeros, edge_base, ebstride, nslot, 1);
  }
  k_fold23<<<1, 256, 0, stream>>>(S2, S3, F + 256, nslot);
  k_bnrelu<<<dim3(1600,8), 256, 0, stream>>>((float*)d_out, F + 256, g3, be3, g4, be4);
}